// Round 5
// baseline (762.712 us; speedup 1.0000x reference)
//
#include <hip/hip_runtime.h>
#include <hip/hip_bf16.h>
#include <math.h>

typedef __bf16 bf16;
typedef __bf16 bf16x8 __attribute__((ext_vector_type(8)));
typedef float f32x4 __attribute__((ext_vector_type(4)));
typedef long longx2 __attribute__((ext_vector_type(2)));

#define C_DIM 512
#define S_DIM 8192

__device__ __forceinline__ void async_ld16(const void* g, void* l) {
    __builtin_amdgcn_global_load_lds(
        (const __attribute__((address_space(1))) unsigned int*)g,
        (__attribute__((address_space(3))) unsigned int*)l, 16, 0, 0);
}

// f32 -> OCP e4m3 via HW cvt (gfx950: v_cvt_pk_fp8_f32 emits OCP format)
__device__ __forceinline__ unsigned char to_fp8(float v) {
    return (unsigned char)(__builtin_amdgcn_cvt_pk_fp8_f32(v, v, 0, false) & 0xFF);
}

// ---------------- Kernel 0: dtype detect (wave ballot) + aux zeroing -----
// flag[0] = dtype flag; flag[16] = slot counter; flag[64..320) = cnt[256]
__global__ void detect_kernel(const unsigned short* __restrict__ xu, int* __restrict__ flag) {
    int j = threadIdx.x;   // 64 threads
    for (int i = 16 + j; i < 320; i += 64) flag[i] = 0;   // zero counter + cnt[256]
    unsigned e = (xu[2 * j] >> 7) & 0xFF;
    unsigned long long m = __ballot(e >= 90 && e <= 140);
    if (j == 0) *flag = (__popcll(m) >= 48) ? 1 : 0;   // 1 = bf16, 0 = fp32
}

// ---------------- Kernel 0b: all 4 weights -> bf16 (one launch) ----------
__global__ __launch_bounds__(256) void convert_kernel(const void* __restrict__ s0,
                                                      const void* __restrict__ s1,
                                                      const void* __restrict__ s2,
                                                      const void* __restrict__ s3,
                                                      bf16* __restrict__ dst,
                                                      const int* __restrict__ flag) {
    int y = blockIdx.y;
    const void* srcs[4] = {s0, s1, s2, s3};
    const void* src = srcs[y];
    int i = blockIdx.x * 256 + threadIdx.x;
    bf16* d = dst + (size_t)y * 262144;
    if (*flag) {
        volatile const bf16* s = (volatile const bf16*)src;
        d[i] = s[i];
    } else {
        volatile const float* s = (volatile const float*)src;
        d[i] = (bf16)s[i];
    }
}

// ---------------- Kernel 1: per-token inverse RMS norm (coalesced) -------
__global__ __launch_bounds__(256) void rms_kernel(const void* __restrict__ x,
                                                  float* __restrict__ r,
                                                  const int* __restrict__ flag) {
    __shared__ float red[4][64];
    int b  = blockIdx.x >> 7;
    int s0 = (blockIdx.x & 127) * 64;
    int sl = threadIdx.x & 63;
    int cq = threadIdx.x >> 6;   // 0..3 -> 128-channel slab
    float acc = 0.f;
    if (*flag) {
        const bf16* xp = (const bf16*)x + ((size_t)b * C_DIM + cq * 128) * S_DIM + s0 + sl;
        for (int c = 0; c < 128; ++c) { float v = (float)xp[(size_t)c * S_DIM]; acc += v * v; }
    } else {
        const float* xp = (const float*)x + ((size_t)b * C_DIM + cq * 128) * S_DIM + s0 + sl;
        for (int c = 0; c < 128; ++c) { float v = xp[(size_t)c * S_DIM]; acc += v * v; }
    }
    red[cq][sl] = acc;
    __syncthreads();
    if (cq == 0) {
        float t = red[0][sl] + red[1][sl] + red[2][sl] + red[3][sl];
        r[b * S_DIM + s0 + sl] = 22.627416997969522f / fmaxf(sqrtf(t), 1e-12f);
    }
}

// ------------- Kernel 2: transpose+scale -> hn[b][s][c] (token-major) ----
__global__ __launch_bounds__(256) void hn_kernel(const void* __restrict__ x,
                                                 const void* __restrict__ gamma,
                                                 const float* __restrict__ r,
                                                 bf16* __restrict__ hn,
                                                 const int* __restrict__ flag) {
    __shared__ float tile[64][65];
    int f  = *flag;
    int b  = blockIdx.z;
    int c0 = blockIdx.y * 64;
    int s0 = blockIdx.x * 64;
    int col = threadIdx.x & 63;
    int row = threadIdx.x >> 6;
    if (f) {
        const bf16* xp = (const bf16*)x + ((size_t)b * C_DIM + c0) * S_DIM + s0;
        for (int i = 0; i < 16; ++i)
            tile[row + i * 4][col] = (float)xp[(size_t)(row + i * 4) * S_DIM + col];
    } else {
        const float* xp = (const float*)x + ((size_t)b * C_DIM + c0) * S_DIM + s0;
        for (int i = 0; i < 16; ++i)
            tile[row + i * 4][col] = xp[(size_t)(row + i * 4) * S_DIM + col];
    }
    __syncthreads();
    float g;
    if (f) g = (float)((const bf16*)gamma)[c0 + col];
    else   g = ((const float*)gamma)[c0 + col];
    bf16* hp = hn + ((size_t)b * S_DIM + s0) * C_DIM + c0;
    for (int i = 0; i < 16; ++i) {
        int s_l = row + i * 4;
        float rv = r[b * S_DIM + s0 + s_l];
        hp[(size_t)s_l * C_DIM + col] = (bf16)(tile[col][s_l] * rv * g);
    }
}

// ------------- Kernel 3a: fused QKV GEMM --------------------------------
// One A-tile staging feeds three weight tiles: 48 MFMA per 32-K step.
// out q: fp8 token-major [m][n]
// out k: fp8 b128-paired frag tiles (see attn QK loop)
// out v: fp8 b128-paired frag tiles (see attn PV loop)
__global__ __launch_bounds__(256, 2) void gemm_qkv_kernel(const bf16* __restrict__ A,
                                                          const bf16* __restrict__ Wq,
                                                          const bf16* __restrict__ Wk,
                                                          const bf16* __restrict__ Wv,
                                                          const void* __restrict__ bq,
                                                          const void* __restrict__ bk,
                                                          const void* __restrict__ bv,
                                                          unsigned char* __restrict__ oq,
                                                          unsigned char* __restrict__ ok,
                                                          unsigned char* __restrict__ ov,
                                                          const int* __restrict__ flag) {
    __shared__ bf16 As[128 * 40];
    __shared__ bf16 Bqs[128 * 40];
    __shared__ bf16 Bks[128 * 40];
    __shared__ bf16 Bvs[128 * 40];
    int f  = *flag;
    int m0 = blockIdx.x * 128;
    int n0 = blockIdx.y * 128;
    int tid  = threadIdx.x;
    int lane = tid & 63;
    int wave = tid >> 6;
    int wm = (wave & 1) * 64;
    int wn = (wave >> 1) * 64;
    int l15  = lane & 15;
    int quad = lane >> 4;

    f32x4 aq[4][4] = {}, ak[4][4] = {}, av[4][4] = {};
    for (int k0 = 0; k0 < C_DIM; k0 += 32) {
        __syncthreads();
        for (int u = tid; u < 512; u += 256) {
            int rr = u >> 2;
            int cc = (u & 3) * 8;
            *(bf16x8*)&As[rr * 40 + cc]  = *(const bf16x8*)&A [(size_t)(m0 + rr) * C_DIM + k0 + cc];
            *(bf16x8*)&Bqs[rr * 40 + cc] = *(const bf16x8*)&Wq[(size_t)(n0 + rr) * C_DIM + k0 + cc];
            *(bf16x8*)&Bks[rr * 40 + cc] = *(const bf16x8*)&Wk[(size_t)(n0 + rr) * C_DIM + k0 + cc];
            *(bf16x8*)&Bvs[rr * 40 + cc] = *(const bf16x8*)&Wv[(size_t)(n0 + rr) * C_DIM + k0 + cc];
        }
        __syncthreads();
        bf16x8 af[4];
#pragma unroll
        for (int i = 0; i < 4; ++i)
            af[i] = *(bf16x8*)&As[(wm + i * 16 + l15) * 40 + quad * 8];
#pragma unroll
        for (int j = 0; j < 4; ++j) {
            int boff = (wn + j * 16 + l15) * 40 + quad * 8;
            bf16x8 b0 = *(bf16x8*)&Bqs[boff];
#pragma unroll
            for (int i = 0; i < 4; ++i)
                aq[i][j] = __builtin_amdgcn_mfma_f32_16x16x32_bf16(af[i], b0, aq[i][j], 0, 0, 0);
            bf16x8 b1 = *(bf16x8*)&Bks[boff];
#pragma unroll
            for (int i = 0; i < 4; ++i)
                ak[i][j] = __builtin_amdgcn_mfma_f32_16x16x32_bf16(af[i], b1, ak[i][j], 0, 0, 0);
            bf16x8 b2 = *(bf16x8*)&Bvs[boff];
#pragma unroll
            for (int i = 0; i < 4; ++i)
                av[i][j] = __builtin_amdgcn_mfma_f32_16x16x32_bf16(af[i], b2, av[i][j], 0, 0, 0);
        }
    }
#pragma unroll
    for (int i = 0; i < 4; ++i)
#pragma unroll
        for (int j = 0; j < 4; ++j) {
            int n = n0 + wn + j * 16 + l15;
            float bvq = f ? (float)((const bf16*)bq)[n] : ((const float*)bq)[n];
            float bvk = f ? (float)((const bf16*)bk)[n] : ((const float*)bk)[n];
            float bvv = f ? (float)((const bf16*)bv)[n] : ((const float*)bv)[n];
#pragma unroll
            for (int rg = 0; rg < 4; ++rg) {
                int m = m0 + wm + i * 16 + quad * 4 + rg;
                oq[(size_t)m * C_DIM + n] = to_fp8(aq[i][j][rg] + bvq);
                // K: chunk (m>>5), pair p=n>>6, quad=(n>>3)&3, key=m&31, h=(n>>5)&1
                size_t ik = (size_t)(m >> 5) * 16384 +
                            (((size_t)(n >> 6) * 4 + ((n >> 3) & 3)) * 32 + (m & 31)) * 16 +
                            ((n >> 5) & 1) * 8 + (n & 7);
                ok[ik] = to_fp8(ak[i][j][rg] + bvk);
                // V: chunk (m>>5), kq=(m>>3)&3, dnp=n>>5, cl=n&15, h=(n>>4)&1, k8=m&7
                size_t iv = (size_t)(m >> 5) * 16384 + ((size_t)(m >> 3) & 3) * 4096 +
                            (((size_t)(n >> 5) * 16 + (n & 15)) * 2 + ((n >> 4) & 1)) * 8 + (m & 7);
                ov[iv] = to_fp8(av[i][j][rg] + bvv);
            }
        }
}

// ------------- Kernel 3b: output GEMM  out = A.Wo + bias + resid ---------
// Epilogue routes each wave's 64n x 64m tile through wave-private LDS so
// stores and resid loads are 64-B contiguous runs along s (out[b][c][s]).
__global__ __launch_bounds__(256, 2) void gemm_kernel(const bf16* __restrict__ A,
                                                      const bf16* __restrict__ W,
                                                      const void* __restrict__ bias,
                                                      const void* __restrict__ resid,
                                                      void* __restrict__ out,
                                                      const int* __restrict__ flag) {
    __shared__ bf16 As[128 * 40];
    __shared__ bf16 Bs[128 * 40];
    __shared__ float tbuf[4][16][65];   // per-wave transpose tile (16n x 64m)
    int f  = *flag;
    int m0 = blockIdx.x * 128;
    int n0 = blockIdx.y * 128;
    int tid  = threadIdx.x;
    int lane = tid & 63;
    int wave = tid >> 6;
    int wm = (wave & 1) * 64;
    int wn = (wave >> 1) * 64;
    int l15  = lane & 15;
    int quad = lane >> 4;

    f32x4 acc[4][4] = {};
    for (int k0 = 0; k0 < C_DIM; k0 += 32) {
        __syncthreads();
        for (int u = tid; u < 512; u += 256) {
            int rrow = u >> 2;
            int cc = (u & 3) * 8;
            *(bf16x8*)&As[rrow * 40 + cc] =
                *(const bf16x8*)&A[(size_t)(m0 + rrow) * C_DIM + k0 + cc];
            *(bf16x8*)&Bs[rrow * 40 + cc] =
                *(const bf16x8*)&W[(size_t)(n0 + rrow) * C_DIM + k0 + cc];
        }
        __syncthreads();
        bf16x8 af[4], bfr[4];
#pragma unroll
        for (int i = 0; i < 4; ++i)
            af[i] = *(bf16x8*)&As[(wm + i * 16 + l15) * 40 + quad * 8];
#pragma unroll
        for (int j = 0; j < 4; ++j)
            bfr[j] = *(bf16x8*)&Bs[(wn + j * 16 + l15) * 40 + quad * 8];
#pragma unroll
        for (int i = 0; i < 4; ++i)
#pragma unroll
            for (int j = 0; j < 4; ++j)
                acc[i][j] = __builtin_amdgcn_mfma_f32_16x16x32_bf16(af[i], bfr[j], acc[i][j], 0, 0, 0);
    }
    // ---- coalesced epilogue via per-wave LDS transpose ----
    int rrow = lane >> 2;          // 0..15: n row within 16-group
    int mseg = (lane & 3) << 4;    // 0/16/32/48: m segment
    int m_base = m0 + wm;
    int bb = m_base >> 13;
    int sb = (m_base & 8191) + mseg;
#pragma unroll
    for (int j = 0; j < 4; ++j) {
#pragma unroll
        for (int i = 0; i < 4; ++i)
            *(f32x4*)&tbuf[wave][l15][i * 16 + quad * 4] = acc[i][j];
        int n = n0 + wn + j * 16 + rrow;
        if (f) {
            float bv = (float)((const bf16*)bias)[n];
            bf16* opb = (bf16*)out + ((size_t)bb * C_DIM + n) * S_DIM + sb;
            const bf16* rpb = (const bf16*)resid + ((size_t)bb * C_DIM + n) * S_DIM + sb;
#pragma unroll
            for (int t = 0; t < 2; ++t) {
                bf16x8 rv = *(const bf16x8*)&rpb[t * 8];
                bf16x8 o8;
#pragma unroll
                for (int e = 0; e < 8; ++e)
                    o8[e] = (bf16)(tbuf[wave][rrow][mseg + t * 8 + e] + bv + (float)rv[e]);
                *(bf16x8*)&opb[t * 8] = o8;
            }
        } else {
            float bv = ((const float*)bias)[n];
            float* opf = (float*)out + ((size_t)bb * C_DIM + n) * S_DIM + sb;
            const float* rpf = (const float*)resid + ((size_t)bb * C_DIM + n) * S_DIM + sb;
#pragma unroll
            for (int t = 0; t < 4; ++t) {
                float4 rv = *(const float4*)&rpf[t * 4];
                float4 v;
                v.x = tbuf[wave][rrow][mseg + t * 4 + 0] + bv + rv.x;
                v.y = tbuf[wave][rrow][mseg + t * 4 + 1] + bv + rv.y;
                v.z = tbuf[wave][rrow][mseg + t * 4 + 2] + bv + rv.z;
                v.w = tbuf[wave][rrow][mseg + t * 4 + 3] + bv + rv.w;
                *(float4*)&opf[t * 4] = v;
            }
        }
    }
}

// ------------- Kernel 4a: V-direct split flash attention -----------------
// Round-3 single-barrier structure, but V is read directly from global
// (L2/L3-resident, per-lane-contiguous frag layout, 4 waves/block share the
// chunk via L1) -> no V LDS, no V staging. LDS = K double-buffer (32 KB) +
// Ps = ~35 KB -> 3-4 blocks/CU (12-16 waves) vs round-3's 2 (8 waves).
// K and V frags paired for b128 reads (2 K-steps / 2 dn per load).
// 768 blocks x 48 chunks: exactly balanced, one barrier per chunk with a
// full iteration of prefetch slack.
__global__ __launch_bounds__(256, 3) void attn_split_kernel(const unsigned char* __restrict__ q,
                                                            const unsigned char* __restrict__ k,
                                                            const unsigned char* __restrict__ vt,
                                                            bf16* __restrict__ part,
                                                            float* __restrict__ lsum,
                                                            int* __restrict__ counter,
                                                            int* __restrict__ cnt,
                                                            int* __restrict__ slist) {
    __shared__ unsigned char Ks[2][16384]; // 32 KB
    __shared__ unsigned char Ps[4][16 * 40];
    __shared__ int slot_sh;
    int tid  = threadIdx.x;
    int lane = tid & 63;
    int wave = tid >> 6;
    int l15  = lane & 15;
    int quad = lane >> 4;

    // ---- decode start state for g0 = 48*blockIdx (uniform scalar) ----
    int g0 = blockIdx.x * 48;
    int b_ = (g0 >= 18432) ? 1 : 0;
    int r  = g0 - b_ * 18432;
    int f_ = 0;
    while (r >= 256 * (f_ + 1) * (f_ + 2)) ++f_;
    int L   = 32 * (f_ + 1);
    int rr  = r - 256 * f_ * (f_ + 1);
    int tif = rr / L;
    int cw  = rr - tif * L;

    // ---- Q fragments for current tile (16 K-steps over C=512) ----
    long qf[16];
    {
        int qbase = (f_ * 16 + tif) * 64 + wave * 16;
        const unsigned char* qp = q + (size_t)(b_ * S_DIM + qbase + l15) * C_DIM;
#pragma unroll
        for (int ks = 0; ks < 16; ++ks)
            qf[ks] = *(const long*)&qp[ks * 32 + quad * 8];
    }

    f32x4 oacc[32] = {};
    float l_i[4] = {0.f, 0.f, 0.f, 0.f};
    const float scale = 0.044194173824159216f;  // 1/sqrt(512)

    // stage one 16 KB K chunk (wave-uniform LDS base + lane*16)
    auto stageK = [&](int buf, int sb, int sc) {
        const unsigned char* kc = k + ((size_t)(sb * 256 + sc) << 14);
#pragma unroll
        for (int j = 0; j < 4; ++j) {
            int off = (j * 4 + wave) * 1024;
            async_ld16(kc + off + lane * 16, &Ks[buf][off]);
        }
    };

    stageK(0, b_, cw);
    __syncthreads();

    for (int i = 0; i < 48; ++i) {
        int last = (i == 47);
        int nb = b_, nf = f_, nL = L, ntif = tif, ncw = cw + 1;
        int newtile = 0;
        if (ncw == L) {
            ncw = 0; newtile = 1; ntif = tif + 1;
            if (ntif == 16) {
                ntif = 0; nf = f_ + 1; nL = L + 32;
                if (nf == 8) { nf = 0; nL = 32; nb = b_ + 1; }
            }
        }
        if (last) { nb = b_; nf = f_; nL = L; ntif = tif; ncw = cw; newtile = 0; }

        // ---- prefetch K(i+1) into the other buffer ----
        stageK((i + 1) & 1, nb, ncw);

        const unsigned char* kb = Ks[i & 1];
        const unsigned char* vg = vt + ((size_t)(b_ * 256 + cw) << 14);

        // S = q . k^T : b128 reads, 2 K-steps per load
        f32x4 st[2] = {};
#pragma unroll
        for (int nt = 0; nt < 2; ++nt) {
#pragma unroll
            for (int p = 0; p < 8; ++p) {
                longx2 kf = *(const longx2*)&kb[(((p * 4 + quad) * 32) + nt * 16 + l15) * 16];
                st[nt] = __builtin_amdgcn_mfma_f32_16x16x32_fp8_fp8(qf[2 * p], kf[0], st[nt], 0, 0, 0);
                st[nt] = __builtin_amdgcn_mfma_f32_16x16x32_fp8_fp8(qf[2 * p + 1], kf[1], st[nt], 0, 0, 0);
            }
        }
        // softmax-lite: raw exp (scores bounded), per-lane l accumulation
        float p0[4], p1[4];
#pragma unroll
        for (int rg = 0; rg < 4; ++rg) {
            p0[rg] = __expf(st[0][rg] * scale);
            p1[rg] = __expf(st[1][rg] * scale);
            l_i[rg] += p0[rg] + p1[rg];
        }
        // P (C layout) -> per-wave fp8 LDS scratch -> A layout (same-wave)
        unsigned char* pw = Ps[wave];
#pragma unroll
        for (int rg = 0; rg < 4; ++rg) {
            pw[(quad * 4 + rg) * 40 + l15] = to_fp8(p0[rg]);
            pw[(quad * 4 + rg) * 40 + 16 + l15] = to_fp8(p1[rg]);
        }
        long pf = *(const long*)&pw[l15 * 40 + quad * 8];
        // PV: V frags direct from global, b128 = 2 dn per load
#pragma unroll
        for (int dnp = 0; dnp < 16; ++dnp) {
            longx2 vf = *(const longx2*)&vg[quad * 4096 + (dnp * 16 + l15) * 16];
            oacc[2 * dnp]     = __builtin_amdgcn_mfma_f32_16x16x32_fp8_fp8(pf, vf[0], oacc[2 * dnp], 0, 0, 0);
            oacc[2 * dnp + 1] = __builtin_amdgcn_mfma_f32_16x16x32_fp8_fp8(pf, vf[1], oacc[2 * dnp + 1], 0, 0, 0);
        }

        // ---- flush segment at tile boundary / end of span ----
        if (last || newtile) {
            int ord = b_ * 128 + f_ * 16 + tif;   // q-tile ordinal 0..255
            if (tid == 0) {
                int s = atomicAdd(counter, 1);
                int pos = atomicAdd(&cnt[ord], 1);
                slist[ord * 8 + pos] = s;
                slot_sh = s;
            }
            __syncthreads();
            int slot = slot_sh;
#pragma unroll
            for (int rg = 0; rg < 4; ++rg)
                for (int d = 1; d < 16; d <<= 1)
                    l_i[rg] += __shfl_xor(l_i[rg], d);
            float rinv[4];
#pragma unroll
            for (int rg = 0; rg < 4; ++rg) rinv[rg] = 1.f / l_i[rg];
            bf16* pp = part + ((size_t)slot * 64 + wave * 16) * C_DIM;
#pragma unroll
            for (int dn = 0; dn < 32; ++dn)
#pragma unroll
                for (int rg = 0; rg < 4; ++rg)
                    pp[(size_t)(quad * 4 + rg) * C_DIM + dn * 16 + l15] =
                        (bf16)(oacc[dn][rg] * rinv[rg]);
            if (l15 == 0) {
#pragma unroll
                for (int rg = 0; rg < 4; ++rg)
                    lsum[slot * 64 + wave * 16 + quad * 4 + rg] = l_i[rg];
            }
            if (!last) {
#pragma unroll
                for (int dn = 0; dn < 32; ++dn) oacc[dn] = (f32x4){0.f, 0.f, 0.f, 0.f};
#pragma unroll
                for (int rg = 0; rg < 4; ++rg) l_i[rg] = 0.f;
                int nqbase = (nf * 16 + ntif) * 64 + wave * 16;
                const unsigned char* qp = q + (size_t)(nb * S_DIM + nqbase + l15) * C_DIM;
#pragma unroll
                for (int ks = 0; ks < 16; ++ks)
                    qf[ks] = *(const long*)&qp[ks * 32 + quad * 8];
            }
        }
        b_ = nb; f_ = nf; L = nL; tif = ntif; cw = ncw;
        __syncthreads();   // drains K prefetch; all waves done with Ks[i&1]
    }
}

// ------------- Kernel 4b: non-split fallback flash attention -------------
__global__ __launch_bounds__(256, 2) void attn_kernel(const unsigned char* __restrict__ q,
                                                      const unsigned char* __restrict__ k,
                                                      const unsigned char* __restrict__ vt,
                                                      bf16* __restrict__ ob) {
    __shared__ unsigned char Ks[2][16384];
    __shared__ unsigned char Ps[4][16 * 40];
    int id = blockIdx.x;
    int b = id >> 7;
    int t = id & 127;
    int q0 = t * 64;
    int kc1 = ((t >> 4) + 1) << 10;
    int tid  = threadIdx.x;
    int lane = tid & 63;
    int wave = tid >> 6;
    int l15  = lane & 15;
    int quad = lane >> 4;
    int qbase = q0 + wave * 16;
    int nchunks = kc1 >> 5;

    long qf[16];
    const unsigned char* qp = q + (size_t)(b * S_DIM + qbase + l15) * C_DIM;
#pragma unroll
    for (int ks = 0; ks < 16; ++ks)
        qf[ks] = *(const long*)&qp[ks * 32 + quad * 8];

    f32x4 oacc[32] = {};
    float l_i[4] = {0.f, 0.f, 0.f, 0.f};
    const float scale = 0.044194173824159216f;

    const unsigned char* kbase = k  + ((size_t)(b * 256) << 14);
    const unsigned char* vbase = vt + ((size_t)(b * 256) << 14);

#pragma unroll
    for (int j = 0; j < 4; ++j) {
        int base = (j * 4 + wave) * 1024;
        async_ld16(kbase + base + lane * 16, &Ks[0][base]);
    }
    __syncthreads();

    for (int p = 0; p < nchunks; ++p) {
        int pn = (p + 1 < nchunks) ? (p + 1) : p;
#pragma unroll
        for (int j = 0; j < 4; ++j) {
            int base = (j * 4 + wave) * 1024;
            async_ld16(kbase + ((size_t)pn << 14) + base + lane * 16, &Ks[(p + 1) & 1][base]);
        }
        const unsigned char* kb = Ks[p & 1];
        const unsigned char* vg = vbase + ((size_t)p << 14);
        f32x4 st[2] = {};
#pragma unroll
        for (int nt = 0; nt < 2; ++nt) {
#pragma unroll
            for (int pp = 0; pp < 8; ++pp) {
                longx2 kf = *(const longx2*)&kb[(((pp * 4 + quad) * 32) + nt * 16 + l15) * 16];
                st[nt] = __builtin_amdgcn_mfma_f32_16x16x32_fp8_fp8(qf[2 * pp], kf[0], st[nt], 0, 0, 0);
                st[nt] = __builtin_amdgcn_mfma_f32_16x16x32_fp8_fp8(qf[2 * pp + 1], kf[1], st[nt], 0, 0, 0);
            }
        }
        float p0[4], p1[4];
#pragma unroll
        for (int rg = 0; rg < 4; ++rg) {
            p0[rg] = __expf(st[0][rg] * scale);
            p1[rg] = __expf(st[1][rg] * scale);
            l_i[rg] += p0[rg] + p1[rg];
        }
        unsigned char* pw = Ps[wave];
#pragma unroll
        for (int rg = 0; rg < 4; ++rg) {
            pw[(quad * 4 + rg) * 40 + l15] = to_fp8(p0[rg]);
            pw[(quad * 4 + rg) * 40 + 16 + l15] = to_fp8(p1[rg]);
        }
        long pf = *(const long*)&pw[l15 * 40 + quad * 8];
#pragma unroll
        for (int dnp = 0; dnp < 16; ++dnp) {
            longx2 vf = *(const longx2*)&vg[quad * 4096 + (dnp * 16 + l15) * 16];
            oacc[2 * dnp]     = __builtin_amdgcn_mfma_f32_16x16x32_fp8_fp8(pf, vf[0], oacc[2 * dnp], 0, 0, 0);
            oacc[2 * dnp + 1] = __builtin_amdgcn_mfma_f32_16x16x32_fp8_fp8(pf, vf[1], oacc[2 * dnp + 1], 0, 0, 0);
        }
        __syncthreads();
    }
#pragma unroll
    for (int rg = 0; rg < 4; ++rg)
        for (int d = 1; d < 16; d <<= 1)
            l_i[rg] += __shfl_xor(l_i[rg], d);
    float rinv[4];
#pragma unroll
    for (int rg = 0; rg < 4; ++rg) rinv[rg] = 1.f / l_i[rg];
    bf16* op = ob + (size_t)(b * S_DIM + qbase) * C_DIM;
#pragma unroll
    for (int dn = 0; dn < 32; ++dn)
#pragma unroll
        for (int rg = 0; rg < 4; ++rg)
            op[(size_t)(quad * 4 + rg) * C_DIM + dn * 16 + l15] =
                (bf16)(oacc[dn][rg] * rinv[rg]);
}

// ------------- Kernel 5: split-K combine (slot-list weighted sum) --------
__global__ __launch_bounds__(256) void combine_kernel(const bf16* __restrict__ part,
                                                      const float* __restrict__ lsum,
                                                      bf16* __restrict__ ob,
                                                      const int* __restrict__ cnt,
                                                      const int* __restrict__ slist) {
    int id = blockIdx.x;            // q-tile ordinal 0..255
    int b  = id >> 7;
    int q0 = (id & 127) * 64;
    int U  = cnt[id];               // 1..7 segments
    int qq = threadIdx.x >> 2;      // 0..63
    int cr = threadIdx.x & 3;       // 128-ch segment
    int sl[8];
    float w[8];
    float D = 0.f;
    for (int u = 0; u < U; ++u) {
        sl[u] = slist[id * 8 + u];
        w[u] = lsum[sl[u] * 64 + qq];
        D += w[u];
    }
    float Dinv = 1.f / D;
    for (int u = 0; u < U; ++u) w[u] *= Dinv;
    bf16* op = ob + (size_t)(b * S_DIM + q0 + qq) * C_DIM + cr * 128;
    for (int ch = 0; ch < 16; ++ch) {
        float acc[8] = {};
        for (int u = 0; u < U; ++u) {
            bf16x8 pv = *(const bf16x8*)&part[((size_t)sl[u] * 64 + qq) * C_DIM + cr * 128 + ch * 8];
#pragma unroll
            for (int j = 0; j < 8; ++j) acc[j] += w[u] * (float)pv[j];
        }
        bf16x8 o8;
#pragma unroll
        for (int j = 0; j < 8; ++j) o8[j] = (bf16)acc[j];
        *(bf16x8*)&op[ch * 8] = o8;
    }
}

extern "C" void kernel_launch(void* const* d_in, const int* in_sizes, int n_in,
                              void* d_out, int out_size, void* d_ws, size_t ws_size,
                              hipStream_t stream) {
    const void* x     = d_in[0];
    const void* gamma = d_in[1];
    const void* wq    = d_in[2];
    const void* bq    = d_in[3];
    const void* wk    = d_in[4];
    const void* bk    = d_in[5];
    const void* wv    = d_in[6];
    const void* bv    = d_in[7];
    const void* wo    = d_in[8];
    const void* bo    = d_in[9];

    char* ws = (char*)d_ws;
    int*   flag    = (int*)ws;                 // [0]=flag, [16]=slot counter, [64..320)=cnt
    int*   counter = (int*)(ws + 64);
    int*   cntp    = (int*)(ws + 256);
    int*   slist   = (int*)(ws + 0x12000);     // 256 q-tiles x 8 slots (8 KB)
    float* r_buf   = (float*)(ws + 4096);
    bf16* wqb = (bf16*)(ws + 0x20000);   // 4 weights contiguous, 512 KB each
    bf16* wkb = (bf16*)(ws + 0xA0000);
    bf16* wvb = (bf16*)(ws + 0x120000);
    bf16* wob = (bf16*)(ws + 0x1A0000);
    float* lsum_buf = (float*)(ws + 0x240000);                  // <=1024 slots x 64 f32 (256 KB)
    bf16* hn  = (bf16*)(ws + 0x400000);                         // 16 MB
    unsigned char* qb  = (unsigned char*)(ws + 0x1400000);      // 8 MB (fp8)
    unsigned char* kb  = (unsigned char*)(ws + 0x1C00000);      // 8 MB
    unsigned char* vtb = (unsigned char*)(ws + 0x2400000);      // 8 MB
    bf16* ob  = (bf16*)(ws + 0x2C00000);                        // 16 MB
    bf16* part = (bf16*)(ws + 0x5400000);                       // <=1024 slots x 64 KB (64 MB)

    const size_t ws_needed_split = 0x5400000ull + 1024ull * 64 * 512 * 2;
    int split = (ws_size >= ws_needed_split) ? 1 : 0;

    hipLaunchKernelGGL(detect_kernel, dim3(1), dim3(64), 0, stream,
                       (const unsigned short*)x, flag);
    hipLaunchKernelGGL(convert_kernel, dim3(1024, 4), dim3(256), 0, stream,
                       wq, wk, wv, wo, wqb, flag);
    hipLaunchKernelGGL(rms_kernel, dim3(256), dim3(256), 0, stream, x, r_buf, flag);
    hipLaunchKernelGGL(hn_kernel, dim3(128, 8, 2), dim3(256), 0, stream, x, gamma, r_buf, hn, flag);
    hipLaunchKernelGGL(gemm_qkv_kernel, dim3(128, 4), dim3(256), 0, stream,
                       hn, wqb, wkb, wvb, bq, bk, bv, qb, kb, vtb, flag);
    if (split) {
        hipLaunchKernelGGL(attn_split_kernel, dim3(768), dim3(256), 0, stream,
                           qb, kb, vtb, part, lsum_buf, counter, cntp, slist);
        hipLaunchKernelGGL(combine_kernel, dim3(256), dim3(256), 0, stream,
                           part, lsum_buf, ob, cntp, slist);
    } else {
        hipLaunchKernelGGL(attn_kernel, dim3(256), dim3(256), 0, stream, qb, kb, vtb, ob);
    }
    hipLaunchKernelGGL(gemm_kernel, dim3(128, 4), dim3(256), 0, stream, ob, wob, bo, x, d_out, flag);
}

// Round 7
// 375.590 us; speedup vs baseline: 2.0307x; 2.0307x over previous
//
#include <hip/hip_runtime.h>
#include <hip/hip_bf16.h>
#include <math.h>

typedef __bf16 bf16;
typedef __bf16 bf16x8 __attribute__((ext_vector_type(8)));
typedef float f32x4 __attribute__((ext_vector_type(4)));
typedef long longx2 __attribute__((ext_vector_type(2)));

#define C_DIM 512
#define S_DIM 8192

__device__ __forceinline__ void async_ld16(const void* g, void* l) {
    __builtin_amdgcn_global_load_lds(
        (const __attribute__((address_space(1))) unsigned int*)g,
        (__attribute__((address_space(3))) unsigned int*)l, 16, 0, 0);
}

// f32 -> OCP e4m3 via HW cvt (gfx950: v_cvt_pk_fp8_f32 emits OCP format)
__device__ __forceinline__ unsigned char to_fp8(float v) {
    return (unsigned char)(__builtin_amdgcn_cvt_pk_fp8_f32(v, v, 0, false) & 0xFF);
}

// ---------------- Kernel 0: dtype detect (wave ballot) + aux zeroing -----
// flag[0] = dtype flag; flag[16] = slot counter; flag[64..320) = cnt[256]
__global__ void detect_kernel(const unsigned short* __restrict__ xu, int* __restrict__ flag) {
    int j = threadIdx.x;   // 64 threads
    for (int i = 16 + j; i < 320; i += 64) flag[i] = 0;   // zero counter + cnt[256]
    unsigned e = (xu[2 * j] >> 7) & 0xFF;
    unsigned long long m = __ballot(e >= 90 && e <= 140);
    if (j == 0) *flag = (__popcll(m) >= 48) ? 1 : 0;   // 1 = bf16, 0 = fp32
}

// ---------------- Kernel 0b: all 4 weights -> bf16 (one launch) ----------
__global__ __launch_bounds__(256) void convert_kernel(const void* __restrict__ s0,
                                                      const void* __restrict__ s1,
                                                      const void* __restrict__ s2,
                                                      const void* __restrict__ s3,
                                                      bf16* __restrict__ dst,
                                                      const int* __restrict__ flag) {
    int y = blockIdx.y;
    const void* srcs[4] = {s0, s1, s2, s3};
    const void* src = srcs[y];
    int i = blockIdx.x * 256 + threadIdx.x;
    bf16* d = dst + (size_t)y * 262144;
    if (*flag) {
        volatile const bf16* s = (volatile const bf16*)src;
        d[i] = s[i];
    } else {
        volatile const float* s = (volatile const float*)src;
        d[i] = (bf16)s[i];
    }
}

// ---------------- Kernel 1: per-token inverse RMS norm (coalesced) -------
__global__ __launch_bounds__(256) void rms_kernel(const void* __restrict__ x,
                                                  float* __restrict__ r,
                                                  const int* __restrict__ flag) {
    __shared__ float red[4][64];
    int b  = blockIdx.x >> 7;
    int s0 = (blockIdx.x & 127) * 64;
    int sl = threadIdx.x & 63;
    int cq = threadIdx.x >> 6;   // 0..3 -> 128-channel slab
    float acc = 0.f;
    if (*flag) {
        const bf16* xp = (const bf16*)x + ((size_t)b * C_DIM + cq * 128) * S_DIM + s0 + sl;
        for (int c = 0; c < 128; ++c) { float v = (float)xp[(size_t)c * S_DIM]; acc += v * v; }
    } else {
        const float* xp = (const float*)x + ((size_t)b * C_DIM + cq * 128) * S_DIM + s0 + sl;
        for (int c = 0; c < 128; ++c) { float v = xp[(size_t)c * S_DIM]; acc += v * v; }
    }
    red[cq][sl] = acc;
    __syncthreads();
    if (cq == 0) {
        float t = red[0][sl] + red[1][sl] + red[2][sl] + red[3][sl];
        r[b * S_DIM + s0 + sl] = 22.627416997969522f / fmaxf(sqrtf(t), 1e-12f);
    }
}

// ------------- Kernel 2: transpose+scale -> hn[b][s][c] (token-major) ----
__global__ __launch_bounds__(256) void hn_kernel(const void* __restrict__ x,
                                                 const void* __restrict__ gamma,
                                                 const float* __restrict__ r,
                                                 bf16* __restrict__ hn,
                                                 const int* __restrict__ flag) {
    __shared__ float tile[64][65];
    int f  = *flag;
    int b  = blockIdx.z;
    int c0 = blockIdx.y * 64;
    int s0 = blockIdx.x * 64;
    int col = threadIdx.x & 63;
    int row = threadIdx.x >> 6;
    if (f) {
        const bf16* xp = (const bf16*)x + ((size_t)b * C_DIM + c0) * S_DIM + s0;
        for (int i = 0; i < 16; ++i)
            tile[row + i * 4][col] = (float)xp[(size_t)(row + i * 4) * S_DIM + col];
    } else {
        const float* xp = (const float*)x + ((size_t)b * C_DIM + c0) * S_DIM + s0;
        for (int i = 0; i < 16; ++i)
            tile[row + i * 4][col] = xp[(size_t)(row + i * 4) * S_DIM + col];
    }
    __syncthreads();
    float g;
    if (f) g = (float)((const bf16*)gamma)[c0 + col];
    else   g = ((const float*)gamma)[c0 + col];
    bf16* hp = hn + ((size_t)b * S_DIM + s0) * C_DIM + c0;
    for (int i = 0; i < 16; ++i) {
        int s_l = row + i * 4;
        float rv = r[b * S_DIM + s0 + s_l];
        hp[(size_t)s_l * C_DIM + col] = (bf16)(tile[col][s_l] * rv * g);
    }
}

// ------------- Kernel 3a: fused QKV GEMM --------------------------------
// One A-tile staging feeds three weight tiles: 48 MFMA per 32-K step.
// out q: fp8 token-major [m][n]
// out k: fp8 b128-paired K frags (HW-verified r5 layout)
// out v: fp8 b128-paired V frags (HW-verified r5 layout)
__global__ __launch_bounds__(256, 2) void gemm_qkv_kernel(const bf16* __restrict__ A,
                                                          const bf16* __restrict__ Wq,
                                                          const bf16* __restrict__ Wk,
                                                          const bf16* __restrict__ Wv,
                                                          const void* __restrict__ bq,
                                                          const void* __restrict__ bk,
                                                          const void* __restrict__ bv,
                                                          unsigned char* __restrict__ oq,
                                                          unsigned char* __restrict__ ok,
                                                          unsigned char* __restrict__ ov,
                                                          const int* __restrict__ flag) {
    __shared__ bf16 As[128 * 40];
    __shared__ bf16 Bqs[128 * 40];
    __shared__ bf16 Bks[128 * 40];
    __shared__ bf16 Bvs[128 * 40];
    int f  = *flag;
    int m0 = blockIdx.x * 128;
    int n0 = blockIdx.y * 128;
    int tid  = threadIdx.x;
    int lane = tid & 63;
    int wave = tid >> 6;
    int wm = (wave & 1) * 64;
    int wn = (wave >> 1) * 64;
    int l15  = lane & 15;
    int quad = lane >> 4;

    f32x4 aq[4][4] = {}, ak[4][4] = {}, av[4][4] = {};
    for (int k0 = 0; k0 < C_DIM; k0 += 32) {
        __syncthreads();
        for (int u = tid; u < 512; u += 256) {
            int rr = u >> 2;
            int cc = (u & 3) * 8;
            *(bf16x8*)&As[rr * 40 + cc]  = *(const bf16x8*)&A [(size_t)(m0 + rr) * C_DIM + k0 + cc];
            *(bf16x8*)&Bqs[rr * 40 + cc] = *(const bf16x8*)&Wq[(size_t)(n0 + rr) * C_DIM + k0 + cc];
            *(bf16x8*)&Bks[rr * 40 + cc] = *(const bf16x8*)&Wk[(size_t)(n0 + rr) * C_DIM + k0 + cc];
            *(bf16x8*)&Bvs[rr * 40 + cc] = *(const bf16x8*)&Wv[(size_t)(n0 + rr) * C_DIM + k0 + cc];
        }
        __syncthreads();
        bf16x8 af[4];
#pragma unroll
        for (int i = 0; i < 4; ++i)
            af[i] = *(bf16x8*)&As[(wm + i * 16 + l15) * 40 + quad * 8];
#pragma unroll
        for (int j = 0; j < 4; ++j) {
            int boff = (wn + j * 16 + l15) * 40 + quad * 8;
            bf16x8 b0 = *(bf16x8*)&Bqs[boff];
#pragma unroll
            for (int i = 0; i < 4; ++i)
                aq[i][j] = __builtin_amdgcn_mfma_f32_16x16x32_bf16(af[i], b0, aq[i][j], 0, 0, 0);
            bf16x8 b1 = *(bf16x8*)&Bks[boff];
#pragma unroll
            for (int i = 0; i < 4; ++i)
                ak[i][j] = __builtin_amdgcn_mfma_f32_16x16x32_bf16(af[i], b1, ak[i][j], 0, 0, 0);
            bf16x8 b2 = *(bf16x8*)&Bvs[boff];
#pragma unroll
            for (int i = 0; i < 4; ++i)
                av[i][j] = __builtin_amdgcn_mfma_f32_16x16x32_bf16(af[i], b2, av[i][j], 0, 0, 0);
        }
    }
#pragma unroll
    for (int i = 0; i < 4; ++i)
#pragma unroll
        for (int j = 0; j < 4; ++j) {
            int n = n0 + wn + j * 16 + l15;
            float bvq = f ? (float)((const bf16*)bq)[n] : ((const float*)bq)[n];
            float bvk = f ? (float)((const bf16*)bk)[n] : ((const float*)bk)[n];
            float bvv = f ? (float)((const bf16*)bv)[n] : ((const float*)bv)[n];
#pragma unroll
            for (int rg = 0; rg < 4; ++rg) {
                int m = m0 + wm + i * 16 + quad * 4 + rg;
                oq[(size_t)m * C_DIM + n] = to_fp8(aq[i][j][rg] + bvq);
                // K: chunk (m>>5), group (n>>6)*4+((n>>3)&3), key m&31, half (n>>5)&1, byte n&7
                size_t ik = (size_t)(m >> 5) * 16384 +
                            (((size_t)(n >> 6) * 4 + ((n >> 3) & 3)) * 32 + (m & 31)) * 16 +
                            ((n >> 5) & 1) * 8 + (n & 7);
                ok[ik] = to_fp8(ak[i][j][rg] + bvk);
                // V: chunk (m>>5), kq=(m>>3)&3, pair=(n>>5), cl=n&15, h=(n>>4)&1, k8=m&7
                size_t iv = (size_t)(m >> 5) * 16384 + ((size_t)(m >> 3) & 3) * 4096 +
                            (((size_t)(n >> 5) * 16 + (n & 15)) * 2 + ((n >> 4) & 1)) * 8 + (m & 7);
                ov[iv] = to_fp8(av[i][j][rg] + bvv);
            }
        }
}

// ------------- Kernel 3b: output GEMM  out = A.Wo + bias + resid ---------
// (round-3 epilogue: direct scattered stores; best-measured config)
__global__ __launch_bounds__(256, 2) void gemm_kernel(const bf16* __restrict__ A,
                                                      const bf16* __restrict__ W,
                                                      const void* __restrict__ bias,
                                                      const void* __restrict__ resid,
                                                      void* __restrict__ out,
                                                      const int* __restrict__ flag) {
    __shared__ bf16 As[128 * 40];
    __shared__ bf16 Bs[128 * 40];
    int f  = *flag;
    int m0 = blockIdx.x * 128;
    int n0 = blockIdx.y * 128;
    int tid  = threadIdx.x;
    int lane = tid & 63;
    int wave = tid >> 6;
    int wm = (wave & 1) * 64;
    int wn = (wave >> 1) * 64;
    int l15  = lane & 15;
    int quad = lane >> 4;

    f32x4 acc[4][4] = {};
    for (int k0 = 0; k0 < C_DIM; k0 += 32) {
        __syncthreads();
        for (int u = tid; u < 512; u += 256) {
            int rrow = u >> 2;
            int cc = (u & 3) * 8;
            *(bf16x8*)&As[rrow * 40 + cc] =
                *(const bf16x8*)&A[(size_t)(m0 + rrow) * C_DIM + k0 + cc];
            *(bf16x8*)&Bs[rrow * 40 + cc] =
                *(const bf16x8*)&W[(size_t)(n0 + rrow) * C_DIM + k0 + cc];
        }
        __syncthreads();
        bf16x8 af[4], bfr[4];
#pragma unroll
        for (int i = 0; i < 4; ++i)
            af[i] = *(bf16x8*)&As[(wm + i * 16 + l15) * 40 + quad * 8];
#pragma unroll
        for (int j = 0; j < 4; ++j)
            bfr[j] = *(bf16x8*)&Bs[(wn + j * 16 + l15) * 40 + quad * 8];
#pragma unroll
        for (int i = 0; i < 4; ++i)
#pragma unroll
            for (int j = 0; j < 4; ++j)
                acc[i][j] = __builtin_amdgcn_mfma_f32_16x16x32_bf16(af[i], bfr[j], acc[i][j], 0, 0, 0);
    }
    if (f) {
        bf16* op = (bf16*)out;
        const bf16* rp = (const bf16*)resid;
#pragma unroll
        for (int i = 0; i < 4; ++i)
#pragma unroll
            for (int j = 0; j < 4; ++j)
#pragma unroll
                for (int rg = 0; rg < 4; ++rg) {
                    int m = m0 + wm + i * 16 + quad * 4 + rg;
                    int n = n0 + wn + j * 16 + l15;
                    float bv = (float)((const bf16*)bias)[n];
                    int b = m >> 13, s = m & 8191;
                    size_t idx = ((size_t)b * C_DIM + n) * S_DIM + s;
                    op[idx] = (bf16)(acc[i][j][rg] + bv + (float)rp[idx]);
                }
    } else {
        float* op = (float*)out;
        const float* rp = (const float*)resid;
#pragma unroll
        for (int i = 0; i < 4; ++i)
#pragma unroll
            for (int j = 0; j < 4; ++j)
#pragma unroll
                for (int rg = 0; rg < 4; ++rg) {
                    int m = m0 + wm + i * 16 + quad * 4 + rg;
                    int n = n0 + wn + j * 16 + l15;
                    float bv = ((const float*)bias)[n];
                    int b = m >> 13, s = m & 8191;
                    size_t idx = ((size_t)b * C_DIM + n) * S_DIM + s;
                    op[idx] = acc[i][j][rg] + bv + rp[idx];
                }
    }
}

// ------------- Kernel 4a: balanced split flash attention (r3 structure) --
// 512 blocks x 256 threads x 72 chunks, 2 blocks/CU desynchronized, one
// barrier per chunk with a full iteration of prefetch slack. Inner loops
// use the r5-verified paired-b128 K/V layouts: ds_read count halved in
// both QK and PV. P scratch stays in the r3 byte-wise form.
__global__ __launch_bounds__(256, 2) void attn_split_kernel(const unsigned char* __restrict__ q,
                                                            const unsigned char* __restrict__ k,
                                                            const unsigned char* __restrict__ vt,
                                                            bf16* __restrict__ part,
                                                            float* __restrict__ lsum,
                                                            int* __restrict__ counter,
                                                            int* __restrict__ cnt,
                                                            int* __restrict__ slist) {
    __shared__ unsigned char Ks[2][16384];   // 32 KB
    __shared__ unsigned char Vs[2][16384];   // 32 KB
    __shared__ unsigned char Ps[4][16 * 40]; // 2.5 KB
    __shared__ int slot_sh;
    int tid  = threadIdx.x;
    int lane = tid & 63;
    int wave = tid >> 6;
    int l15  = lane & 15;
    int quad = lane >> 4;

    // ---- decode start state for g0 = 72*blockIdx (uniform scalar) ----
    int g0 = blockIdx.x * 72;
    int b_ = (g0 >= 18432) ? 1 : 0;
    int r  = g0 - b_ * 18432;
    int f_ = 0;
    while (r >= 256 * (f_ + 1) * (f_ + 2)) ++f_;
    int L   = 32 * (f_ + 1);
    int rr  = r - 256 * f_ * (f_ + 1);
    int tif = rr / L;
    int cw  = rr - tif * L;

    // ---- Q fragments for current tile (16 K-steps over C=512) ----
    long qf[16];
    {
        int qbase = (f_ * 16 + tif) * 64 + wave * 16;
        const unsigned char* qp = q + (size_t)(b_ * S_DIM + qbase + l15) * C_DIM;
#pragma unroll
        for (int ks = 0; ks < 16; ++ks)
            qf[ks] = *(const long*)&qp[ks * 32 + quad * 8];
    }

    f32x4 oacc[32] = {};
    float l_i[4] = {0.f, 0.f, 0.f, 0.f};
    const float scale = 0.044194173824159216f;  // 1/sqrt(512)

    // prefetch chunk 0 into buffer 0 (wave-uniform LDS base + lane*16)
    {
        const unsigned char* ka = k  + ((size_t)(b_ * 256 + cw) << 14);
        const unsigned char* va = vt + ((size_t)(b_ * 256 + cw) << 14);
#pragma unroll
        for (int j = 0; j < 4; ++j) {
            int base = (j * 4 + wave) * 1024;
            async_ld16(ka + base + lane * 16, &Ks[0][base]);
            async_ld16(va + base + lane * 16, &Vs[0][base]);
        }
    }
    __syncthreads();

    for (int i = 0; i < 72; ++i) {
        int last = (i == 71);
        int nb = b_, nf = f_, nL = L, ntif = tif, ncw = cw + 1;
        int newtile = 0;
        if (ncw == L) {
            ncw = 0; newtile = 1; ntif = tif + 1;
            if (ntif == 16) {
                ntif = 0; nf = f_ + 1; nL = L + 32;
                if (nf == 8) { nf = 0; nL = 32; nb = b_ + 1; }
            }
        }
        if (last) { nb = b_; nf = f_; nL = L; ntif = tif; ncw = cw; newtile = 0; }

        // ---- prefetch next chunk into the other buffer ----
        {
            const unsigned char* ka = k  + ((size_t)(nb * 256 + ncw) << 14);
            const unsigned char* va = vt + ((size_t)(nb * 256 + ncw) << 14);
            unsigned char* kd = Ks[(i + 1) & 1];
            unsigned char* vd = Vs[(i + 1) & 1];
#pragma unroll
            for (int j = 0; j < 4; ++j) {
                int base = (j * 4 + wave) * 1024;
                async_ld16(ka + base + lane * 16, kd + base);
                async_ld16(va + base + lane * 16, vd + base);
            }
        }
        const unsigned char* kb = Ks[i & 1];
        const unsigned char* vb = Vs[i & 1];

        // S = q . k^T : paired b128 reads, 2 k-steps per load (r5 loop)
        f32x4 st[2] = {};
#pragma unroll
        for (int nt = 0; nt < 2; ++nt) {
#pragma unroll
            for (int pp = 0; pp < 8; ++pp) {
                longx2 kf = *(const longx2*)&kb[(((pp * 4 + quad) * 32) + nt * 16 + l15) * 16];
                st[nt] = __builtin_amdgcn_mfma_f32_16x16x32_fp8_fp8(qf[2 * pp], kf[0], st[nt], 0, 0, 0);
                st[nt] = __builtin_amdgcn_mfma_f32_16x16x32_fp8_fp8(qf[2 * pp + 1], kf[1], st[nt], 0, 0, 0);
            }
        }
        // softmax-lite: raw exp (scores bounded), per-lane l accumulation
        float p0[4], p1[4];
#pragma unroll
        for (int rg = 0; rg < 4; ++rg) {
            p0[rg] = __expf(st[0][rg] * scale);
            p1[rg] = __expf(st[1][rg] * scale);
            l_i[rg] += p0[rg] + p1[rg];
        }
        // P (C layout) -> per-wave fp8 LDS scratch -> A layout (same-wave)
        unsigned char* pw = Ps[wave];
#pragma unroll
        for (int rg = 0; rg < 4; ++rg) {
            pw[(quad * 4 + rg) * 40 + l15] = to_fp8(p0[rg]);
            pw[(quad * 4 + rg) * 40 + 16 + l15] = to_fp8(p1[rg]);
        }
        long pf = *(const long*)&pw[l15 * 40 + quad * 8];
        // PV: paired b128 reads = 2 dn per load (r5 layout, LDS buffer)
#pragma unroll
        for (int dnp = 0; dnp < 16; ++dnp) {
            longx2 vf = *(const longx2*)&vb[quad * 4096 + (dnp * 16 + l15) * 16];
            oacc[2 * dnp]     = __builtin_amdgcn_mfma_f32_16x16x32_fp8_fp8(pf, vf[0], oacc[2 * dnp], 0, 0, 0);
            oacc[2 * dnp + 1] = __builtin_amdgcn_mfma_f32_16x16x32_fp8_fp8(pf, vf[1], oacc[2 * dnp + 1], 0, 0, 0);
        }

        // ---- flush segment at tile boundary / end of span ----
        if (last || newtile) {
            int ord = b_ * 128 + f_ * 16 + tif;   // q-tile ordinal 0..255
            if (tid == 0) {
                int s = atomicAdd(counter, 1);
                int pos = atomicAdd(&cnt[ord], 1);
                slist[ord * 8 + pos] = s;
                slot_sh = s;
            }
            __syncthreads();
            int slot = slot_sh;
#pragma unroll
            for (int rg = 0; rg < 4; ++rg)
                for (int d = 1; d < 16; d <<= 1)
                    l_i[rg] += __shfl_xor(l_i[rg], d);
            float rinv[4];
#pragma unroll
            for (int rg = 0; rg < 4; ++rg) rinv[rg] = 1.f / l_i[rg];
            bf16* pp = part + ((size_t)slot * 64 + wave * 16) * C_DIM;
#pragma unroll
            for (int dn = 0; dn < 32; ++dn)
#pragma unroll
                for (int rg = 0; rg < 4; ++rg)
                    pp[(size_t)(quad * 4 + rg) * C_DIM + dn * 16 + l15] =
                        (bf16)(oacc[dn][rg] * rinv[rg]);
            if (l15 == 0) {
#pragma unroll
                for (int rg = 0; rg < 4; ++rg)
                    lsum[slot * 64 + wave * 16 + quad * 4 + rg] = l_i[rg];
            }
            if (!last) {
#pragma unroll
                for (int dn = 0; dn < 32; ++dn) oacc[dn] = (f32x4){0.f, 0.f, 0.f, 0.f};
#pragma unroll
                for (int rg = 0; rg < 4; ++rg) l_i[rg] = 0.f;
                int nqbase = (nf * 16 + ntif) * 64 + wave * 16;
                const unsigned char* qp = q + (size_t)(nb * S_DIM + nqbase + l15) * C_DIM;
#pragma unroll
                for (int ks = 0; ks < 16; ++ks)
                    qf[ks] = *(const long*)&qp[ks * 32 + quad * 8];
            }
        }
        b_ = nb; f_ = nf; L = nL; tif = ntif; cw = ncw;
        __syncthreads();   // drains prefetch + all waves done with buffers
    }
}

// ------------- Kernel 4b: non-split fallback flash attention -------------
__global__ __launch_bounds__(256, 2) void attn_kernel(const unsigned char* __restrict__ q,
                                                      const unsigned char* __restrict__ k,
                                                      const unsigned char* __restrict__ vt,
                                                      bf16* __restrict__ ob) {
    __shared__ unsigned char Ks[2][16384];
    __shared__ unsigned char Vs[2][16384];
    __shared__ unsigned char Ps[4][16 * 40];
    int id = blockIdx.x;
    int b = id >> 7;
    int t = id & 127;
    int q0 = t * 64;
    int kc1 = ((t >> 4) + 1) << 10;
    int tid  = threadIdx.x;
    int lane = tid & 63;
    int wave = tid >> 6;
    int l15  = lane & 15;
    int quad = lane >> 4;
    int qbase = q0 + wave * 16;
    int nchunks = kc1 >> 5;

    long qf[16];
    const unsigned char* qp = q + (size_t)(b * S_DIM + qbase + l15) * C_DIM;
#pragma unroll
    for (int ks = 0; ks < 16; ++ks)
        qf[ks] = *(const long*)&qp[ks * 32 + quad * 8];

    f32x4 oacc[32] = {};
    float l_i[4] = {0.f, 0.f, 0.f, 0.f};
    const float scale = 0.044194173824159216f;

    const unsigned char* kbase = k  + ((size_t)(b * 256) << 14);
    const unsigned char* vbase = vt + ((size_t)(b * 256) << 14);

#pragma unroll
    for (int j = 0; j < 4; ++j) {
        int base = (j * 4 + wave) * 1024;
        async_ld16(kbase + base + lane * 16, &Ks[0][base]);
        async_ld16(vbase + base + lane * 16, &Vs[0][base]);
    }
    __syncthreads();

    for (int p = 0; p < nchunks; ++p) {
        int pn = (p + 1 < nchunks) ? (p + 1) : p;
        const unsigned char* ksub = kbase + ((size_t)pn << 14);
        const unsigned char* vsub = vbase + ((size_t)pn << 14);
        unsigned char* kd = Ks[(p + 1) & 1];
        unsigned char* vd = Vs[(p + 1) & 1];
#pragma unroll
        for (int j = 0; j < 4; ++j) {
            int base = (j * 4 + wave) * 1024;
            async_ld16(ksub + base + lane * 16, kd + base);
            async_ld16(vsub + base + lane * 16, vd + base);
        }
        const unsigned char* kb = Ks[p & 1];
        const unsigned char* vb = Vs[p & 1];
        f32x4 st[2] = {};
#pragma unroll
        for (int nt = 0; nt < 2; ++nt) {
#pragma unroll
            for (int pp = 0; pp < 8; ++pp) {
                longx2 kf = *(const longx2*)&kb[(((pp * 4 + quad) * 32) + nt * 16 + l15) * 16];
                st[nt] = __builtin_amdgcn_mfma_f32_16x16x32_fp8_fp8(qf[2 * pp], kf[0], st[nt], 0, 0, 0);
                st[nt] = __builtin_amdgcn_mfma_f32_16x16x32_fp8_fp8(qf[2 * pp + 1], kf[1], st[nt], 0, 0, 0);
            }
        }
        float p0[4], p1[4];
#pragma unroll
        for (int rg = 0; rg < 4; ++rg) {
            p0[rg] = __expf(st[0][rg] * scale);
            p1[rg] = __expf(st[1][rg] * scale);
            l_i[rg] += p0[rg] + p1[rg];
        }
        unsigned char* pw = Ps[wave];
#pragma unroll
        for (int rg = 0; rg < 4; ++rg) {
            pw[(quad * 4 + rg) * 40 + l15] = to_fp8(p0[rg]);
            pw[(quad * 4 + rg) * 40 + 16 + l15] = to_fp8(p1[rg]);
        }
        long pf = *(const long*)&pw[l15 * 40 + quad * 8];
#pragma unroll
        for (int dnp = 0; dnp < 16; ++dnp) {
            longx2 vf = *(const longx2*)&vb[quad * 4096 + (dnp * 16 + l15) * 16];
            oacc[2 * dnp]     = __builtin_amdgcn_mfma_f32_16x16x32_fp8_fp8(pf, vf[0], oacc[2 * dnp], 0, 0, 0);
            oacc[2 * dnp + 1] = __builtin_amdgcn_mfma_f32_16x16x32_fp8_fp8(pf, vf[1], oacc[2 * dnp + 1], 0, 0, 0);
        }
        __syncthreads();
    }
#pragma unroll
    for (int rg = 0; rg < 4; ++rg)
        for (int d = 1; d < 16; d <<= 1)
            l_i[rg] += __shfl_xor(l_i[rg], d);
    float rinv[4];
#pragma unroll
    for (int rg = 0; rg < 4; ++rg) rinv[rg] = 1.f / l_i[rg];
    bf16* op = ob + (size_t)(b * S_DIM + qbase) * C_DIM;
#pragma unroll
    for (int dn = 0; dn < 32; ++dn)
#pragma unroll
        for (int rg = 0; rg < 4; ++rg)
            op[(size_t)(quad * 4 + rg) * C_DIM + dn * 16 + l15] =
                (bf16)(oacc[dn][rg] * rinv[rg]);
}

// ------------- Kernel 5: split-K combine (slot-list weighted sum) --------
__global__ __launch_bounds__(256) void combine_kernel(const bf16* __restrict__ part,
                                                      const float* __restrict__ lsum,
                                                      bf16* __restrict__ ob,
                                                      const int* __restrict__ cnt,
                                                      const int* __restrict__ slist) {
    int id = blockIdx.x;            // q-tile ordinal 0..255
    int b  = id >> 7;
    int q0 = (id & 127) * 64;
    int U  = cnt[id];               // 1..~5 segments
    int qq = threadIdx.x >> 2;      // 0..63
    int cr = threadIdx.x & 3;       // 128-ch segment
    int sl[8];
    float w[8];
    float D = 0.f;
    for (int u = 0; u < U; ++u) {
        sl[u] = slist[id * 8 + u];
        w[u] = lsum[sl[u] * 64 + qq];
        D += w[u];
    }
    float Dinv = 1.f / D;
    for (int u = 0; u < U; ++u) w[u] *= Dinv;
    bf16* op = ob + (size_t)(b * S_DIM + q0 + qq) * C_DIM + cr * 128;
    for (int ch = 0; ch < 16; ++ch) {
        float acc[8] = {};
        for (int u = 0; u < U; ++u) {
            bf16x8 pv = *(const bf16x8*)&part[((size_t)sl[u] * 64 + qq) * C_DIM + cr * 128 + ch * 8];
#pragma unroll
            for (int j = 0; j < 8; ++j) acc[j] += w[u] * (float)pv[j];
        }
        bf16x8 o8;
#pragma unroll
        for (int j = 0; j < 8; ++j) o8[j] = (bf16)acc[j];
        *(bf16x8*)&op[ch * 8] = o8;
    }
}

extern "C" void kernel_launch(void* const* d_in, const int* in_sizes, int n_in,
                              void* d_out, int out_size, void* d_ws, size_t ws_size,
                              hipStream_t stream) {
    const void* x     = d_in[0];
    const void* gamma = d_in[1];
    const void* wq    = d_in[2];
    const void* bq    = d_in[3];
    const void* wk    = d_in[4];
    const void* bk    = d_in[5];
    const void* wv    = d_in[6];
    const void* bv    = d_in[7];
    const void* wo    = d_in[8];
    const void* bo    = d_in[9];

    char* ws = (char*)d_ws;
    int*   flag    = (int*)ws;                 // [0]=flag, [16]=slot counter, [64..320)=cnt
    int*   counter = (int*)(ws + 64);
    int*   cntp    = (int*)(ws + 256);
    int*   slist   = (int*)(ws + 0x12000);     // 256 q-tiles x 8 slots (8 KB)
    float* r_buf   = (float*)(ws + 4096);
    bf16* wqb = (bf16*)(ws + 0x20000);   // 4 weights contiguous, 512 KB each
    bf16* wkb = (bf16*)(ws + 0xA0000);
    bf16* wvb = (bf16*)(ws + 0x120000);
    bf16* wob = (bf16*)(ws + 0x1A0000);
    float* lsum_buf = (float*)(ws + 0x240000);                  // <=768 slots x 64 f32
    bf16* hn  = (bf16*)(ws + 0x400000);                         // 16 MB
    unsigned char* qb  = (unsigned char*)(ws + 0x1400000);      // 8 MB (fp8)
    unsigned char* kb  = (unsigned char*)(ws + 0x1C00000);      // 8 MB
    unsigned char* vtb = (unsigned char*)(ws + 0x2400000);      // 8 MB
    bf16* ob  = (bf16*)(ws + 0x2C00000);                        // 16 MB
    bf16* part = (bf16*)(ws + 0x5400000);                       // <=768 slots x 64 x 512 bf16 (50.3 MB)

    const size_t ws_needed_split = 0x5400000ull + 768ull * 64 * 512 * 2;
    int split = (ws_size >= ws_needed_split) ? 1 : 0;

    hipLaunchKernelGGL(detect_kernel, dim3(1), dim3(64), 0, stream,
                       (const unsigned short*)x, flag);
    hipLaunchKernelGGL(convert_kernel, dim3(1024, 4), dim3(256), 0, stream,
                       wq, wk, wv, wo, wqb, flag);
    hipLaunchKernelGGL(rms_kernel, dim3(256), dim3(256), 0, stream, x, r_buf, flag);
    hipLaunchKernelGGL(hn_kernel, dim3(128, 8, 2), dim3(256), 0, stream, x, gamma, r_buf, hn, flag);
    hipLaunchKernelGGL(gemm_qkv_kernel, dim3(128, 4), dim3(256), 0, stream,
                       hn, wqb, wkb, wvb, bq, bk, bv, qb, kb, vtb, flag);
    if (split) {
        hipLaunchKernelGGL(attn_split_kernel, dim3(512), dim3(256), 0, stream,
                           qb, kb, vtb, part, lsum_buf, counter, cntp, slist);
        hipLaunchKernelGGL(combine_kernel, dim3(256), dim3(256), 0, stream,
                           part, lsum_buf, ob, cntp, slist);
    } else {
        hipLaunchKernelGGL(attn_kernel, dim3(256), dim3(256), 0, stream, qb, kb, vtb, ob);
    }
    hipLaunchKernelGGL(gemm_kernel, dim3(128, 4), dim3(256), 0, stream, ob, wob, bo, x, d_out, flag);
}

// Round 8
// 359.451 us; speedup vs baseline: 2.1219x; 1.0449x over previous
//
#include <hip/hip_runtime.h>
#include <hip/hip_bf16.h>
#include <math.h>

typedef __bf16 bf16;
typedef __bf16 bf16x8 __attribute__((ext_vector_type(8)));
typedef float f32x4 __attribute__((ext_vector_type(4)));
typedef long longx2 __attribute__((ext_vector_type(2)));

#define C_DIM 512
#define S_DIM 8192

__device__ __forceinline__ void async_ld16(const void* g, void* l) {
    __builtin_amdgcn_global_load_lds(
        (const __attribute__((address_space(1))) unsigned int*)g,
        (__attribute__((address_space(3))) unsigned int*)l, 16, 0, 0);
}

// f32 -> OCP e4m3 via HW cvt (gfx950: v_cvt_pk_fp8_f32 emits OCP format)
__device__ __forceinline__ unsigned char to_fp8(float v) {
    return (unsigned char)(__builtin_amdgcn_cvt_pk_fp8_f32(v, v, 0, false) & 0xFF);
}

// ---------------- Kernel 0: dtype detect (wave ballot) + aux zeroing -----
// flag[0] = dtype flag; flag[16] = slot counter; flag[64..320) = cnt[256]
__global__ void detect_kernel(const unsigned short* __restrict__ xu, int* __restrict__ flag) {
    int j = threadIdx.x;   // 64 threads
    for (int i = 16 + j; i < 320; i += 64) flag[i] = 0;   // zero counter + cnt[256]
    unsigned e = (xu[2 * j] >> 7) & 0xFF;
    unsigned long long m = __ballot(e >= 90 && e <= 140);
    if (j == 0) *flag = (__popcll(m) >= 48) ? 1 : 0;   // 1 = bf16, 0 = fp32
}

// ---------------- Kernel 0b: all 4 weights -> bf16 (one launch) ----------
__global__ __launch_bounds__(256) void convert_kernel(const void* __restrict__ s0,
                                                      const void* __restrict__ s1,
                                                      const void* __restrict__ s2,
                                                      const void* __restrict__ s3,
                                                      bf16* __restrict__ dst,
                                                      const int* __restrict__ flag) {
    int y = blockIdx.y;
    const void* srcs[4] = {s0, s1, s2, s3};
    const void* src = srcs[y];
    int i = blockIdx.x * 256 + threadIdx.x;
    bf16* d = dst + (size_t)y * 262144;
    if (*flag) {
        volatile const bf16* s = (volatile const bf16*)src;
        d[i] = s[i];
    } else {
        volatile const float* s = (volatile const float*)src;
        d[i] = (bf16)s[i];
    }
}

// ------------- Kernel 1+2 fused: RMS norm + transpose -> hn[b][s][c] -----
// One block = 64 tokens x all 512 channels. Pass 1: load x[c][s] tile
// (coalesced along s), accumulate per-token sumsq, stash bf16 bits in LDS
// (Xs[512][66]: pass-1 writes contiguous u16 = conflict-free; pass-2
// transposed reads at stride 66 u16 = 33 dwords = 1 bank step = free).
// Pass 2: hn[s][c] = x * r * gamma, same store pattern as old hn_kernel.
// Saves one full read of x and one kernel launch vs separate rms+hn.
__global__ __launch_bounds__(256, 2) void rmshn_kernel(const void* __restrict__ x,
                                                       const void* __restrict__ gamma,
                                                       bf16* __restrict__ hn,
                                                       const int* __restrict__ flag) {
    __shared__ unsigned short Xs[512][66];   // 67.6 KB
    __shared__ float red[4][64];
    __shared__ float rbuf[64];
    int f  = *flag;
    int b  = blockIdx.x >> 7;
    int s0 = (blockIdx.x & 127) * 64;
    int col = threadIdx.x & 63;
    int row = threadIdx.x >> 6;
    float acc = 0.f;
    if (f) {
        const unsigned short* xp = (const unsigned short*)x + (size_t)b * C_DIM * S_DIM + s0 + col;
#pragma unroll 4
        for (int cq = 0; cq < 8; ++cq)
            for (int i = 0; i < 16; ++i) {
                int c = cq * 64 + row + i * 4;
                unsigned short u = xp[(size_t)c * S_DIM];
                float v = __uint_as_float(((unsigned int)u) << 16);
                acc += v * v;
                Xs[c][col] = u;
            }
    } else {
        const float* xp = (const float*)x + (size_t)b * C_DIM * S_DIM + s0 + col;
#pragma unroll 4
        for (int cq = 0; cq < 8; ++cq)
            for (int i = 0; i < 16; ++i) {
                int c = cq * 64 + row + i * 4;
                float v = xp[(size_t)c * S_DIM];
                acc += v * v;
                bf16 h = (bf16)v;
                Xs[c][col] = *(unsigned short*)&h;
            }
    }
    red[row][col] = acc;
    __syncthreads();
    if (row == 0) {
        float t = red[0][col] + red[1][col] + red[2][col] + red[3][col];
        rbuf[col] = 22.627416997969522f / fmaxf(sqrtf(t), 1e-12f);
    }
    __syncthreads();
    bf16* hp = hn + ((size_t)b * S_DIM + s0) * C_DIM;
    for (int cq = 0; cq < 8; ++cq) {
        int c = cq * 64 + col;
        float g = f ? (float)((const bf16*)gamma)[c] : ((const float*)gamma)[c];
#pragma unroll 4
        for (int i = 0; i < 16; ++i) {
            int s_l = row + i * 4;
            float v = __uint_as_float(((unsigned int)Xs[c][s_l]) << 16);
            hp[(size_t)s_l * C_DIM + c] = (bf16)(v * rbuf[s_l] * g);
        }
    }
}

// ------------- Kernel 3a: fused QKV GEMM --------------------------------
// One A-tile staging feeds three weight tiles: 48 MFMA per 32-K step.
// out q: fp8 token-major [m][n]
// out k: fp8 b128-paired K frags (HW-verified r5 layout)
// out v: fp8 b128-paired V frags (HW-verified r5 layout)
__global__ __launch_bounds__(256, 2) void gemm_qkv_kernel(const bf16* __restrict__ A,
                                                          const bf16* __restrict__ Wq,
                                                          const bf16* __restrict__ Wk,
                                                          const bf16* __restrict__ Wv,
                                                          const void* __restrict__ bq,
                                                          const void* __restrict__ bk,
                                                          const void* __restrict__ bv,
                                                          unsigned char* __restrict__ oq,
                                                          unsigned char* __restrict__ ok,
                                                          unsigned char* __restrict__ ov,
                                                          const int* __restrict__ flag) {
    __shared__ bf16 As[128 * 40];
    __shared__ bf16 Bqs[128 * 40];
    __shared__ bf16 Bks[128 * 40];
    __shared__ bf16 Bvs[128 * 40];
    int f  = *flag;
    int m0 = blockIdx.x * 128;
    int n0 = blockIdx.y * 128;
    int tid  = threadIdx.x;
    int lane = tid & 63;
    int wave = tid >> 6;
    int wm = (wave & 1) * 64;
    int wn = (wave >> 1) * 64;
    int l15  = lane & 15;
    int quad = lane >> 4;

    f32x4 aq[4][4] = {}, ak[4][4] = {}, av[4][4] = {};
    for (int k0 = 0; k0 < C_DIM; k0 += 32) {
        __syncthreads();
        for (int u = tid; u < 512; u += 256) {
            int rr = u >> 2;
            int cc = (u & 3) * 8;
            *(bf16x8*)&As[rr * 40 + cc]  = *(const bf16x8*)&A [(size_t)(m0 + rr) * C_DIM + k0 + cc];
            *(bf16x8*)&Bqs[rr * 40 + cc] = *(const bf16x8*)&Wq[(size_t)(n0 + rr) * C_DIM + k0 + cc];
            *(bf16x8*)&Bks[rr * 40 + cc] = *(const bf16x8*)&Wk[(size_t)(n0 + rr) * C_DIM + k0 + cc];
            *(bf16x8*)&Bvs[rr * 40 + cc] = *(const bf16x8*)&Wv[(size_t)(n0 + rr) * C_DIM + k0 + cc];
        }
        __syncthreads();
        bf16x8 af[4];
#pragma unroll
        for (int i = 0; i < 4; ++i)
            af[i] = *(bf16x8*)&As[(wm + i * 16 + l15) * 40 + quad * 8];
#pragma unroll
        for (int j = 0; j < 4; ++j) {
            int boff = (wn + j * 16 + l15) * 40 + quad * 8;
            bf16x8 b0 = *(bf16x8*)&Bqs[boff];
#pragma unroll
            for (int i = 0; i < 4; ++i)
                aq[i][j] = __builtin_amdgcn_mfma_f32_16x16x32_bf16(af[i], b0, aq[i][j], 0, 0, 0);
            bf16x8 b1 = *(bf16x8*)&Bks[boff];
#pragma unroll
            for (int i = 0; i < 4; ++i)
                ak[i][j] = __builtin_amdgcn_mfma_f32_16x16x32_bf16(af[i], b1, ak[i][j], 0, 0, 0);
            bf16x8 b2 = *(bf16x8*)&Bvs[boff];
#pragma unroll
            for (int i = 0; i < 4; ++i)
                av[i][j] = __builtin_amdgcn_mfma_f32_16x16x32_bf16(af[i], b2, av[i][j], 0, 0, 0);
        }
    }
#pragma unroll
    for (int i = 0; i < 4; ++i)
#pragma unroll
        for (int j = 0; j < 4; ++j) {
            int n = n0 + wn + j * 16 + l15;
            float bvq = f ? (float)((const bf16*)bq)[n] : ((const float*)bq)[n];
            float bvk = f ? (float)((const bf16*)bk)[n] : ((const float*)bk)[n];
            float bvv = f ? (float)((const bf16*)bv)[n] : ((const float*)bv)[n];
#pragma unroll
            for (int rg = 0; rg < 4; ++rg) {
                int m = m0 + wm + i * 16 + quad * 4 + rg;
                oq[(size_t)m * C_DIM + n] = to_fp8(aq[i][j][rg] + bvq);
                // K: chunk (m>>5), group (n>>6)*4+((n>>3)&3), key m&31, half (n>>5)&1, byte n&7
                size_t ik = (size_t)(m >> 5) * 16384 +
                            (((size_t)(n >> 6) * 4 + ((n >> 3) & 3)) * 32 + (m & 31)) * 16 +
                            ((n >> 5) & 1) * 8 + (n & 7);
                ok[ik] = to_fp8(ak[i][j][rg] + bvk);
                // V: chunk (m>>5), kq=(m>>3)&3, pair=(n>>5), cl=n&15, h=(n>>4)&1, k8=m&7
                size_t iv = (size_t)(m >> 5) * 16384 + ((size_t)(m >> 3) & 3) * 4096 +
                            (((size_t)(n >> 5) * 16 + (n & 15)) * 2 + ((n >> 4) & 1)) * 8 + (m & 7);
                ov[iv] = to_fp8(av[i][j][rg] + bvv);
            }
        }
}

// ------------- Kernel 3b: output GEMM  out = A.Wo + bias + resid ---------
// (round-3 epilogue: direct scattered stores; best-measured config)
__global__ __launch_bounds__(256, 2) void gemm_kernel(const bf16* __restrict__ A,
                                                      const bf16* __restrict__ W,
                                                      const void* __restrict__ bias,
                                                      const void* __restrict__ resid,
                                                      void* __restrict__ out,
                                                      const int* __restrict__ flag) {
    __shared__ bf16 As[128 * 40];
    __shared__ bf16 Bs[128 * 40];
    int f  = *flag;
    int m0 = blockIdx.x * 128;
    int n0 = blockIdx.y * 128;
    int tid  = threadIdx.x;
    int lane = tid & 63;
    int wave = tid >> 6;
    int wm = (wave & 1) * 64;
    int wn = (wave >> 1) * 64;
    int l15  = lane & 15;
    int quad = lane >> 4;

    f32x4 acc[4][4] = {};
    for (int k0 = 0; k0 < C_DIM; k0 += 32) {
        __syncthreads();
        for (int u = tid; u < 512; u += 256) {
            int rrow = u >> 2;
            int cc = (u & 3) * 8;
            *(bf16x8*)&As[rrow * 40 + cc] =
                *(const bf16x8*)&A[(size_t)(m0 + rrow) * C_DIM + k0 + cc];
            *(bf16x8*)&Bs[rrow * 40 + cc] =
                *(const bf16x8*)&W[(size_t)(n0 + rrow) * C_DIM + k0 + cc];
        }
        __syncthreads();
        bf16x8 af[4], bfr[4];
#pragma unroll
        for (int i = 0; i < 4; ++i)
            af[i] = *(bf16x8*)&As[(wm + i * 16 + l15) * 40 + quad * 8];
#pragma unroll
        for (int j = 0; j < 4; ++j)
            bfr[j] = *(bf16x8*)&Bs[(wn + j * 16 + l15) * 40 + quad * 8];
#pragma unroll
        for (int i = 0; i < 4; ++i)
#pragma unroll
            for (int j = 0; j < 4; ++j)
                acc[i][j] = __builtin_amdgcn_mfma_f32_16x16x32_bf16(af[i], bfr[j], acc[i][j], 0, 0, 0);
    }
    if (f) {
        bf16* op = (bf16*)out;
        const bf16* rp = (const bf16*)resid;
#pragma unroll
        for (int i = 0; i < 4; ++i)
#pragma unroll
            for (int j = 0; j < 4; ++j)
#pragma unroll
                for (int rg = 0; rg < 4; ++rg) {
                    int m = m0 + wm + i * 16 + quad * 4 + rg;
                    int n = n0 + wn + j * 16 + l15;
                    float bv = (float)((const bf16*)bias)[n];
                    int b = m >> 13, s = m & 8191;
                    size_t idx = ((size_t)b * C_DIM + n) * S_DIM + s;
                    op[idx] = (bf16)(acc[i][j][rg] + bv + (float)rp[idx]);
                }
    } else {
        float* op = (float*)out;
        const float* rp = (const float*)resid;
#pragma unroll
        for (int i = 0; i < 4; ++i)
#pragma unroll
            for (int j = 0; j < 4; ++j)
#pragma unroll
                for (int rg = 0; rg < 4; ++rg) {
                    int m = m0 + wm + i * 16 + quad * 4 + rg;
                    int n = n0 + wn + j * 16 + l15;
                    float bv = ((const float*)bias)[n];
                    int b = m >> 13, s = m & 8191;
                    size_t idx = ((size_t)b * C_DIM + n) * S_DIM + s;
                    op[idx] = acc[i][j][rg] + bv + rp[idx];
                }
    }
}

// ------------- Kernel 4a: balanced split flash attention -----------------
// r7 structure (512 blocks x 72 chunks, paired-b128 K/V reads, one barrier
// per chunk) + this round: XCD-chunked block swizzle (contiguous key spans
// per XCD L2), s_setprio(1) around MFMA clusters, 4-chain QK (8-deep
// dependent chains instead of 16-deep).
__global__ __launch_bounds__(256, 2) void attn_split_kernel(const unsigned char* __restrict__ q,
                                                            const unsigned char* __restrict__ k,
                                                            const unsigned char* __restrict__ vt,
                                                            bf16* __restrict__ part,
                                                            float* __restrict__ lsum,
                                                            int* __restrict__ counter,
                                                            int* __restrict__ cnt,
                                                            int* __restrict__ slist) {
    __shared__ unsigned char Ks[2][16384];   // 32 KB
    __shared__ unsigned char Vs[2][16384];   // 32 KB
    __shared__ unsigned char Ps[4][16 * 40]; // 2.5 KB
    __shared__ int slot_sh;
    int tid  = threadIdx.x;
    int lane = tid & 63;
    int wave = tid >> 6;
    int l15  = lane & 15;
    int quad = lane >> 4;

    // ---- XCD-chunked swizzle: consecutive virtual ids land on one XCD ----
    int bid = blockIdx.x;
    int vb  = (bid & 7) * 64 + (bid >> 3);   // 512 = 8 XCDs x 64 chunks, bijective
    int g0 = vb * 72;
    int b_ = (g0 >= 18432) ? 1 : 0;
    int r  = g0 - b_ * 18432;
    int f_ = 0;
    while (r >= 256 * (f_ + 1) * (f_ + 2)) ++f_;
    int L   = 32 * (f_ + 1);
    int rr  = r - 256 * f_ * (f_ + 1);
    int tif = rr / L;
    int cw  = rr - tif * L;

    // ---- Q fragments for current tile (16 K-steps over C=512) ----
    long qf[16];
    {
        int qbase = (f_ * 16 + tif) * 64 + wave * 16;
        const unsigned char* qp = q + (size_t)(b_ * S_DIM + qbase + l15) * C_DIM;
#pragma unroll
        for (int ks = 0; ks < 16; ++ks)
            qf[ks] = *(const long*)&qp[ks * 32 + quad * 8];
    }

    f32x4 oacc[32] = {};
    float l_i[4] = {0.f, 0.f, 0.f, 0.f};
    const float scale = 0.044194173824159216f;  // 1/sqrt(512)

    // prefetch chunk 0 into buffer 0 (wave-uniform LDS base + lane*16)
    {
        const unsigned char* ka = k  + ((size_t)(b_ * 256 + cw) << 14);
        const unsigned char* va = vt + ((size_t)(b_ * 256 + cw) << 14);
#pragma unroll
        for (int j = 0; j < 4; ++j) {
            int base = (j * 4 + wave) * 1024;
            async_ld16(ka + base + lane * 16, &Ks[0][base]);
            async_ld16(va + base + lane * 16, &Vs[0][base]);
        }
    }
    __syncthreads();

    for (int i = 0; i < 72; ++i) {
        int last = (i == 71);
        int nb = b_, nf = f_, nL = L, ntif = tif, ncw = cw + 1;
        int newtile = 0;
        if (ncw == L) {
            ncw = 0; newtile = 1; ntif = tif + 1;
            if (ntif == 16) {
                ntif = 0; nf = f_ + 1; nL = L + 32;
                if (nf == 8) { nf = 0; nL = 32; nb = b_ + 1; }
            }
        }
        if (last) { nb = b_; nf = f_; nL = L; ntif = tif; ncw = cw; newtile = 0; }

        // ---- prefetch next chunk into the other buffer ----
        {
            const unsigned char* ka = k  + ((size_t)(nb * 256 + ncw) << 14);
            const unsigned char* va = vt + ((size_t)(nb * 256 + ncw) << 14);
            unsigned char* kd = Ks[(i + 1) & 1];
            unsigned char* vd = Vs[(i + 1) & 1];
#pragma unroll
            for (int j = 0; j < 4; ++j) {
                int base = (j * 4 + wave) * 1024;
                async_ld16(ka + base + lane * 16, kd + base);
                async_ld16(va + base + lane * 16, vd + base);
            }
        }
        const unsigned char* kb = Ks[i & 1];
        const unsigned char* vb2 = Vs[i & 1];

        // S = q . k^T : paired b128 reads, 4 independent 8-deep chains
        f32x4 sa[2] = {}, sb[2] = {};
        __builtin_amdgcn_s_setprio(1);
#pragma unroll
        for (int pp = 0; pp < 4; ++pp) {
#pragma unroll
            for (int nt = 0; nt < 2; ++nt) {
                longx2 ka2 = *(const longx2*)&kb[(((pp * 4 + quad) * 32) + nt * 16 + l15) * 16];
                longx2 kb2 = *(const longx2*)&kb[((((pp + 4) * 4 + quad) * 32) + nt * 16 + l15) * 16];
                sa[nt] = __builtin_amdgcn_mfma_f32_16x16x32_fp8_fp8(qf[2 * pp],     ka2[0], sa[nt], 0, 0, 0);
                sb[nt] = __builtin_amdgcn_mfma_f32_16x16x32_fp8_fp8(qf[2 * pp + 8], kb2[0], sb[nt], 0, 0, 0);
                sa[nt] = __builtin_amdgcn_mfma_f32_16x16x32_fp8_fp8(qf[2 * pp + 1], ka2[1], sa[nt], 0, 0, 0);
                sb[nt] = __builtin_amdgcn_mfma_f32_16x16x32_fp8_fp8(qf[2 * pp + 9], kb2[1], sb[nt], 0, 0, 0);
            }
        }
        __builtin_amdgcn_s_setprio(0);
        // softmax-lite: raw exp (scores bounded), per-lane l accumulation
        float p0[4], p1[4];
#pragma unroll
        for (int rg = 0; rg < 4; ++rg) {
            p0[rg] = __expf((sa[0][rg] + sb[0][rg]) * scale);
            p1[rg] = __expf((sa[1][rg] + sb[1][rg]) * scale);
            l_i[rg] += p0[rg] + p1[rg];
        }
        // P (C layout) -> per-wave fp8 LDS scratch -> A layout (same-wave)
        unsigned char* pw = Ps[wave];
#pragma unroll
        for (int rg = 0; rg < 4; ++rg) {
            pw[(quad * 4 + rg) * 40 + l15] = to_fp8(p0[rg]);
            pw[(quad * 4 + rg) * 40 + 16 + l15] = to_fp8(p1[rg]);
        }
        long pf = *(const long*)&pw[l15 * 40 + quad * 8];
        // PV: paired b128 reads = 2 dn per load
        __builtin_amdgcn_s_setprio(1);
#pragma unroll
        for (int dnp = 0; dnp < 16; ++dnp) {
            longx2 vf = *(const longx2*)&vb2[quad * 4096 + (dnp * 16 + l15) * 16];
            oacc[2 * dnp]     = __builtin_amdgcn_mfma_f32_16x16x32_fp8_fp8(pf, vf[0], oacc[2 * dnp], 0, 0, 0);
            oacc[2 * dnp + 1] = __builtin_amdgcn_mfma_f32_16x16x32_fp8_fp8(pf, vf[1], oacc[2 * dnp + 1], 0, 0, 0);
        }
        __builtin_amdgcn_s_setprio(0);

        // ---- flush segment at tile boundary / end of span ----
        if (last || newtile) {
            int ord = b_ * 128 + f_ * 16 + tif;   // q-tile ordinal 0..255
            if (tid == 0) {
                int s = atomicAdd(counter, 1);
                int pos = atomicAdd(&cnt[ord], 1);
                slist[ord * 8 + pos] = s;
                slot_sh = s;
            }
            __syncthreads();
            int slot = slot_sh;
#pragma unroll
            for (int rg = 0; rg < 4; ++rg)
                for (int d = 1; d < 16; d <<= 1)
                    l_i[rg] += __shfl_xor(l_i[rg], d);
            float rinv[4];
#pragma unroll
            for (int rg = 0; rg < 4; ++rg) rinv[rg] = 1.f / l_i[rg];
            bf16* pp2 = part + ((size_t)slot * 64 + wave * 16) * C_DIM;
#pragma unroll
            for (int dn = 0; dn < 32; ++dn)
#pragma unroll
                for (int rg = 0; rg < 4; ++rg)
                    pp2[(size_t)(quad * 4 + rg) * C_DIM + dn * 16 + l15] =
                        (bf16)(oacc[dn][rg] * rinv[rg]);
            if (l15 == 0) {
#pragma unroll
                for (int rg = 0; rg < 4; ++rg)
                    lsum[slot * 64 + wave * 16 + quad * 4 + rg] = l_i[rg];
            }
            if (!last) {
#pragma unroll
                for (int dn = 0; dn < 32; ++dn) oacc[dn] = (f32x4){0.f, 0.f, 0.f, 0.f};
#pragma unroll
                for (int rg = 0; rg < 4; ++rg) l_i[rg] = 0.f;
                int nqbase = (nf * 16 + ntif) * 64 + wave * 16;
                const unsigned char* qp = q + (size_t)(nb * S_DIM + nqbase + l15) * C_DIM;
#pragma unroll
                for (int ks = 0; ks < 16; ++ks)
                    qf[ks] = *(const long*)&qp[ks * 32 + quad * 8];
            }
        }
        b_ = nb; f_ = nf; L = nL; tif = ntif; cw = ncw;
        __syncthreads();   // drains prefetch + all waves done with buffers
    }
}

// ------------- Kernel 4b: non-split fallback flash attention -------------
__global__ __launch_bounds__(256, 2) void attn_kernel(const unsigned char* __restrict__ q,
                                                      const unsigned char* __restrict__ k,
                                                      const unsigned char* __restrict__ vt,
                                                      bf16* __restrict__ ob) {
    __shared__ unsigned char Ks[2][16384];
    __shared__ unsigned char Vs[2][16384];
    __shared__ unsigned char Ps[4][16 * 40];
    int id = blockIdx.x;
    int b = id >> 7;
    int t = id & 127;
    int q0 = t * 64;
    int kc1 = ((t >> 4) + 1) << 10;
    int tid  = threadIdx.x;
    int lane = tid & 63;
    int wave = tid >> 6;
    int l15  = lane & 15;
    int quad = lane >> 4;
    int qbase = q0 + wave * 16;
    int nchunks = kc1 >> 5;

    long qf[16];
    const unsigned char* qp = q + (size_t)(b * S_DIM + qbase + l15) * C_DIM;
#pragma unroll
    for (int ks = 0; ks < 16; ++ks)
        qf[ks] = *(const long*)&qp[ks * 32 + quad * 8];

    f32x4 oacc[32] = {};
    float l_i[4] = {0.f, 0.f, 0.f, 0.f};
    const float scale = 0.044194173824159216f;

    const unsigned char* kbase = k  + ((size_t)(b * 256) << 14);
    const unsigned char* vbase = vt + ((size_t)(b * 256) << 14);

#pragma unroll
    for (int j = 0; j < 4; ++j) {
        int base = (j * 4 + wave) * 1024;
        async_ld16(kbase + base + lane * 16, &Ks[0][base]);
        async_ld16(vbase + base + lane * 16, &Vs[0][base]);
    }
    __syncthreads();

    for (int p = 0; p < nchunks; ++p) {
        int pn = (p + 1 < nchunks) ? (p + 1) : p;
        const unsigned char* ksub = kbase + ((size_t)pn << 14);
        const unsigned char* vsub = vbase + ((size_t)pn << 14);
        unsigned char* kd = Ks[(p + 1) & 1];
        unsigned char* vd = Vs[(p + 1) & 1];
#pragma unroll
        for (int j = 0; j < 4; ++j) {
            int base = (j * 4 + wave) * 1024;
            async_ld16(ksub + base + lane * 16, kd + base);
            async_ld16(vsub + base + lane * 16, vd + base);
        }
        const unsigned char* kb = Ks[p & 1];
        const unsigned char* vb = Vs[p & 1];
        f32x4 st[2] = {};
#pragma unroll
        for (int nt = 0; nt < 2; ++nt) {
#pragma unroll
            for (int pp = 0; pp < 8; ++pp) {
                longx2 kf = *(const longx2*)&kb[(((pp * 4 + quad) * 32) + nt * 16 + l15) * 16];
                st[nt] = __builtin_amdgcn_mfma_f32_16x16x32_fp8_fp8(qf[2 * pp], kf[0], st[nt], 0, 0, 0);
                st[nt] = __builtin_amdgcn_mfma_f32_16x16x32_fp8_fp8(qf[2 * pp + 1], kf[1], st[nt], 0, 0, 0);
            }
        }
        float p0[4], p1[4];
#pragma unroll
        for (int rg = 0; rg < 4; ++rg) {
            p0[rg] = __expf(st[0][rg] * scale);
            p1[rg] = __expf(st[1][rg] * scale);
            l_i[rg] += p0[rg] + p1[rg];
        }
        unsigned char* pw = Ps[wave];
#pragma unroll
        for (int rg = 0; rg < 4; ++rg) {
            pw[(quad * 4 + rg) * 40 + l15] = to_fp8(p0[rg]);
            pw[(quad * 4 + rg) * 40 + 16 + l15] = to_fp8(p1[rg]);
        }
        long pf = *(const long*)&pw[l15 * 40 + quad * 8];
#pragma unroll
        for (int dnp = 0; dnp < 16; ++dnp) {
            longx2 vf = *(const longx2*)&vb[quad * 4096 + (dnp * 16 + l15) * 16];
            oacc[2 * dnp]     = __builtin_amdgcn_mfma_f32_16x16x32_fp8_fp8(pf, vf[0], oacc[2 * dnp], 0, 0, 0);
            oacc[2 * dnp + 1] = __builtin_amdgcn_mfma_f32_16x16x32_fp8_fp8(pf, vf[1], oacc[2 * dnp + 1], 0, 0, 0);
        }
        __syncthreads();
    }
#pragma unroll
    for (int rg = 0; rg < 4; ++rg)
        for (int d = 1; d < 16; d <<= 1)
            l_i[rg] += __shfl_xor(l_i[rg], d);
    float rinv[4];
#pragma unroll
    for (int rg = 0; rg < 4; ++rg) rinv[rg] = 1.f / l_i[rg];
    bf16* op = ob + (size_t)(b * S_DIM + qbase) * C_DIM;
#pragma unroll
    for (int dn = 0; dn < 32; ++dn)
#pragma unroll
        for (int rg = 0; rg < 4; ++rg)
            op[(size_t)(quad * 4 + rg) * C_DIM + dn * 16 + l15] =
                (bf16)(oacc[dn][rg] * rinv[rg]);
}

// ------------- Kernel 5: split-K combine (slot-list weighted sum) --------
// grid 256 x 4: blockIdx.y selects a 128-channel quarter (4x parallelism
// vs round-7's 1 block/CU on a BW-bound kernel).
__global__ __launch_bounds__(256) void combine_kernel(const bf16* __restrict__ part,
                                                      const float* __restrict__ lsum,
                                                      bf16* __restrict__ ob,
                                                      const int* __restrict__ cnt,
                                                      const int* __restrict__ slist) {
    int id = blockIdx.x;            // q-tile ordinal 0..255
    int b  = id >> 7;
    int q0 = (id & 127) * 64;
    int U  = cnt[id];               // 1..~5 segments
    int qq = threadIdx.x >> 2;      // 0..63
    int cr = threadIdx.x & 3;       // 32-ch sub-segment
    int cbase = blockIdx.y * 128 + cr * 32;
    int sl[8];
    float w[8];
    float D = 0.f;
    for (int u = 0; u < U; ++u) {
        sl[u] = slist[id * 8 + u];
        w[u] = lsum[sl[u] * 64 + qq];
        D += w[u];
    }
    float Dinv = 1.f / D;
    for (int u = 0; u < U; ++u) w[u] *= Dinv;
    bf16* op = ob + (size_t)(b * S_DIM + q0 + qq) * C_DIM + cbase;
    for (int ch = 0; ch < 4; ++ch) {
        float acc[8] = {};
        for (int u = 0; u < U; ++u) {
            bf16x8 pv = *(const bf16x8*)&part[((size_t)sl[u] * 64 + qq) * C_DIM + cbase + ch * 8];
#pragma unroll
            for (int j = 0; j < 8; ++j) acc[j] += w[u] * (float)pv[j];
        }
        bf16x8 o8;
#pragma unroll
        for (int j = 0; j < 8; ++j) o8[j] = (bf16)acc[j];
        *(bf16x8*)&op[ch * 8] = o8;
    }
}

extern "C" void kernel_launch(void* const* d_in, const int* in_sizes, int n_in,
                              void* d_out, int out_size, void* d_ws, size_t ws_size,
                              hipStream_t stream) {
    const void* x     = d_in[0];
    const void* gamma = d_in[1];
    const void* wq    = d_in[2];
    const void* bq    = d_in[3];
    const void* wk    = d_in[4];
    const void* bk    = d_in[5];
    const void* wv    = d_in[6];
    const void* bv    = d_in[7];
    const void* wo    = d_in[8];
    const void* bo    = d_in[9];

    char* ws = (char*)d_ws;
    int*   flag    = (int*)ws;                 // [0]=flag, [16]=slot counter, [64..320)=cnt
    int*   counter = (int*)(ws + 64);
    int*   cntp    = (int*)(ws + 256);
    int*   slist   = (int*)(ws + 0x12000);     // 256 q-tiles x 8 slots (8 KB)
    bf16* wqb = (bf16*)(ws + 0x20000);   // 4 weights contiguous, 512 KB each
    bf16* wkb = (bf16*)(ws + 0xA0000);
    bf16* wvb = (bf16*)(ws + 0x120000);
    bf16* wob = (bf16*)(ws + 0x1A0000);
    float* lsum_buf = (float*)(ws + 0x240000);                  // <=768 slots x 64 f32
    bf16* hn  = (bf16*)(ws + 0x400000);                         // 16 MB
    unsigned char* qb  = (unsigned char*)(ws + 0x1400000);      // 8 MB (fp8)
    unsigned char* kb  = (unsigned char*)(ws + 0x1C00000);      // 8 MB
    unsigned char* vtb = (unsigned char*)(ws + 0x2400000);      // 8 MB
    bf16* ob  = (bf16*)(ws + 0x2C00000);                        // 16 MB
    bf16* part = (bf16*)(ws + 0x5400000);                       // <=768 slots x 64 x 512 bf16 (50.3 MB)

    const size_t ws_needed_split = 0x5400000ull + 768ull * 64 * 512 * 2;
    int split = (ws_size >= ws_needed_split) ? 1 : 0;

    hipLaunchKernelGGL(detect_kernel, dim3(1), dim3(64), 0, stream,
                       (const unsigned short*)x, flag);
    hipLaunchKernelGGL(convert_kernel, dim3(1024, 4), dim3(256), 0, stream,
                       wq, wk, wv, wo, wqb, flag);
    hipLaunchKernelGGL(rmshn_kernel, dim3(256), dim3(256), 0, stream, x, gamma, hn, flag);
    hipLaunchKernelGGL(gemm_qkv_kernel, dim3(128, 4), dim3(256), 0, stream,
                       hn, wqb, wkb, wvb, bq, bk, bv, qb, kb, vtb, flag);
    if (split) {
        hipLaunchKernelGGL(attn_split_kernel, dim3(512), dim3(256), 0, stream,
                           qb, kb, vtb, part, lsum_buf, counter, cntp, slist);
        hipLaunchKernelGGL(combine_kernel, dim3(256, 4), dim3(256), 0, stream,
                           part, lsum_buf, ob, cntp, slist);
    } else {
        hipLaunchKernelGGL(attn_kernel, dim3(256), dim3(256), 0, stream, qb, kb, vtb, ob);
    }
    hipLaunchKernelGGL(gemm_kernel, dim3(128, 4), dim3(256), 0, stream, ob, wob, bo, x, d_out, flag);
}

// Round 9
// 350.606 us; speedup vs baseline: 2.1754x; 1.0252x over previous
//
#include <hip/hip_runtime.h>
#include <hip/hip_bf16.h>
#include <math.h>

typedef __bf16 bf16;
typedef __bf16 bf16x8 __attribute__((ext_vector_type(8)));
typedef float f32x4 __attribute__((ext_vector_type(4)));
typedef long longx2 __attribute__((ext_vector_type(2)));

#define C_DIM 512
#define S_DIM 8192

__device__ __forceinline__ void async_ld16(const void* g, void* l) {
    __builtin_amdgcn_global_load_lds(
        (const __attribute__((address_space(1))) unsigned int*)g,
        (__attribute__((address_space(3))) unsigned int*)l, 16, 0, 0);
}

// f32 -> OCP e4m3 via HW cvt (gfx950: v_cvt_pk_fp8_f32 emits OCP format)
__device__ __forceinline__ unsigned char to_fp8(float v) {
    return (unsigned char)(__builtin_amdgcn_cvt_pk_fp8_f32(v, v, 0, false) & 0xFF);
}

// ---------------- Kernel 0: dtype detect (wave ballot) + aux zeroing -----
// flag[0] = dtype flag; flag[16] = slot counter; flag[64..320) = cnt[256]
__global__ void detect_kernel(const unsigned short* __restrict__ xu, int* __restrict__ flag) {
    int j = threadIdx.x;   // 64 threads
    for (int i = 16 + j; i < 320; i += 64) flag[i] = 0;   // zero counter + cnt[256]
    unsigned e = (xu[2 * j] >> 7) & 0xFF;
    unsigned long long m = __ballot(e >= 90 && e <= 140);
    if (j == 0) *flag = (__popcll(m) >= 48) ? 1 : 0;   // 1 = bf16, 0 = fp32
}

// ---------------- Kernel 0b: all 4 weights -> bf16 (one launch) ----------
__global__ __launch_bounds__(256) void convert_kernel(const void* __restrict__ s0,
                                                      const void* __restrict__ s1,
                                                      const void* __restrict__ s2,
                                                      const void* __restrict__ s3,
                                                      bf16* __restrict__ dst,
                                                      const int* __restrict__ flag) {
    int y = blockIdx.y;
    const void* srcs[4] = {s0, s1, s2, s3};
    const void* src = srcs[y];
    int i = blockIdx.x * 256 + threadIdx.x;
    bf16* d = dst + (size_t)y * 262144;
    if (*flag) {
        volatile const bf16* s = (volatile const bf16*)src;
        d[i] = s[i];
    } else {
        volatile const float* s = (volatile const float*)src;
        d[i] = (bf16)s[i];
    }
}

// ------------- Kernel 1+2 fused: RMS norm + transpose -> hn[b][s][c] -----
__global__ __launch_bounds__(256, 2) void rmshn_kernel(const void* __restrict__ x,
                                                       const void* __restrict__ gamma,
                                                       bf16* __restrict__ hn,
                                                       const int* __restrict__ flag) {
    __shared__ unsigned short Xs[512][66];   // 67.6 KB
    __shared__ float red[4][64];
    __shared__ float rbuf[64];
    int f  = *flag;
    int b  = blockIdx.x >> 7;
    int s0 = (blockIdx.x & 127) * 64;
    int col = threadIdx.x & 63;
    int row = threadIdx.x >> 6;
    float acc = 0.f;
    if (f) {
        const unsigned short* xp = (const unsigned short*)x + (size_t)b * C_DIM * S_DIM + s0 + col;
#pragma unroll 4
        for (int cq = 0; cq < 8; ++cq)
            for (int i = 0; i < 16; ++i) {
                int c = cq * 64 + row + i * 4;
                unsigned short u = xp[(size_t)c * S_DIM];
                float v = __uint_as_float(((unsigned int)u) << 16);
                acc += v * v;
                Xs[c][col] = u;
            }
    } else {
        const float* xp = (const float*)x + (size_t)b * C_DIM * S_DIM + s0 + col;
#pragma unroll 4
        for (int cq = 0; cq < 8; ++cq)
            for (int i = 0; i < 16; ++i) {
                int c = cq * 64 + row + i * 4;
                float v = xp[(size_t)c * S_DIM];
                acc += v * v;
                bf16 h = (bf16)v;
                Xs[c][col] = *(unsigned short*)&h;
            }
    }
    red[row][col] = acc;
    __syncthreads();
    if (row == 0) {
        float t = red[0][col] + red[1][col] + red[2][col] + red[3][col];
        rbuf[col] = 22.627416997969522f / fmaxf(sqrtf(t), 1e-12f);
    }
    __syncthreads();
    bf16* hp = hn + ((size_t)b * S_DIM + s0) * C_DIM;
    for (int cq = 0; cq < 8; ++cq) {
        int c = cq * 64 + col;
        float g = f ? (float)((const bf16*)gamma)[c] : ((const float*)gamma)[c];
#pragma unroll 4
        for (int i = 0; i < 16; ++i) {
            int s_l = row + i * 4;
            float v = __uint_as_float(((unsigned int)Xs[c][s_l]) << 16);
            hp[(size_t)s_l * C_DIM + c] = (bf16)(v * rbuf[s_l] * g);
        }
    }
}

// ------------- Kernel 3a: fused QKV GEMM --------------------------------
// m97-style staging: linear pitch-32 LDS tiles filled by global_load_lds
// (wave-uniform LDS base + per-lane global addr; 16 B/lane). One A-tile
// staging feeds three weight tiles: 48 MFMA per 32-K step.
__global__ __launch_bounds__(256, 2) void gemm_qkv_kernel(const bf16* __restrict__ A,
                                                          const bf16* __restrict__ Wq,
                                                          const bf16* __restrict__ Wk,
                                                          const bf16* __restrict__ Wv,
                                                          const void* __restrict__ bq,
                                                          const void* __restrict__ bk,
                                                          const void* __restrict__ bv,
                                                          unsigned char* __restrict__ oq,
                                                          unsigned char* __restrict__ ok,
                                                          unsigned char* __restrict__ ov,
                                                          const int* __restrict__ flag) {
    __shared__ bf16 As [128 * 32];   // 8 KB each, linear 64-B rows
    __shared__ bf16 Bqs[128 * 32];
    __shared__ bf16 Bks[128 * 32];
    __shared__ bf16 Bvs[128 * 32];
    int f  = *flag;
    int m0 = blockIdx.x * 128;
    int n0 = blockIdx.y * 128;
    int tid  = threadIdx.x;
    int lane = tid & 63;
    int wave = tid >> 6;
    int wm = (wave & 1) * 64;
    int wn = (wave >> 1) * 64;
    int l15  = lane & 15;
    int quad = lane >> 4;
    int wrow = lane >> 2;          // 0..15: row within 16-row slab
    int wcol = (lane & 3) * 8;     // 0/8/16/24: element quarter

    f32x4 aq[4][4] = {}, ak[4][4] = {}, av[4][4] = {};
    for (int k0 = 0; k0 < C_DIM; k0 += 32) {
        __syncthreads();
#pragma unroll
        for (int j = 0; j < 2; ++j) {
            int rowb = (j * 4 + wave) * 16;
            async_ld16(&A [(size_t)(m0 + rowb + wrow) * C_DIM + k0 + wcol], &As [rowb * 32]);
            async_ld16(&Wq[(size_t)(n0 + rowb + wrow) * C_DIM + k0 + wcol], &Bqs[rowb * 32]);
            async_ld16(&Wk[(size_t)(n0 + rowb + wrow) * C_DIM + k0 + wcol], &Bks[rowb * 32]);
            async_ld16(&Wv[(size_t)(n0 + rowb + wrow) * C_DIM + k0 + wcol], &Bvs[rowb * 32]);
        }
        __syncthreads();   // drains vmcnt -> staged data visible
        bf16x8 af[4];
#pragma unroll
        for (int i = 0; i < 4; ++i)
            af[i] = *(bf16x8*)&As[(wm + i * 16 + l15) * 32 + quad * 8];
#pragma unroll
        for (int j = 0; j < 4; ++j) {
            int boff = (wn + j * 16 + l15) * 32 + quad * 8;
            bf16x8 b0 = *(bf16x8*)&Bqs[boff];
#pragma unroll
            for (int i = 0; i < 4; ++i)
                aq[i][j] = __builtin_amdgcn_mfma_f32_16x16x32_bf16(af[i], b0, aq[i][j], 0, 0, 0);
            bf16x8 b1 = *(bf16x8*)&Bks[boff];
#pragma unroll
            for (int i = 0; i < 4; ++i)
                ak[i][j] = __builtin_amdgcn_mfma_f32_16x16x32_bf16(af[i], b1, ak[i][j], 0, 0, 0);
            bf16x8 b2 = *(bf16x8*)&Bvs[boff];
#pragma unroll
            for (int i = 0; i < 4; ++i)
                av[i][j] = __builtin_amdgcn_mfma_f32_16x16x32_bf16(af[i], b2, av[i][j], 0, 0, 0);
        }
    }
#pragma unroll
    for (int i = 0; i < 4; ++i)
#pragma unroll
        for (int j = 0; j < 4; ++j) {
            int n = n0 + wn + j * 16 + l15;
            float bvq = f ? (float)((const bf16*)bq)[n] : ((const float*)bq)[n];
            float bvk = f ? (float)((const bf16*)bk)[n] : ((const float*)bk)[n];
            float bvv = f ? (float)((const bf16*)bv)[n] : ((const float*)bv)[n];
#pragma unroll
            for (int rg = 0; rg < 4; ++rg) {
                int m = m0 + wm + i * 16 + quad * 4 + rg;
                oq[(size_t)m * C_DIM + n] = to_fp8(aq[i][j][rg] + bvq);
                // K: chunk (m>>5), group (n>>6)*4+((n>>3)&3), key m&31, half (n>>5)&1, byte n&7
                size_t ik = (size_t)(m >> 5) * 16384 +
                            (((size_t)(n >> 6) * 4 + ((n >> 3) & 3)) * 32 + (m & 31)) * 16 +
                            ((n >> 5) & 1) * 8 + (n & 7);
                ok[ik] = to_fp8(ak[i][j][rg] + bvk);
                // V: chunk (m>>5), kq=(m>>3)&3, pair=(n>>5), cl=n&15, h=(n>>4)&1, k8=m&7
                size_t iv = (size_t)(m >> 5) * 16384 + ((size_t)(m >> 3) & 3) * 4096 +
                            (((size_t)(n >> 5) * 16 + (n & 15)) * 2 + ((n >> 4) & 1)) * 8 + (m & 7);
                ov[iv] = to_fp8(av[i][j][rg] + bvv);
            }
        }
}

// ------------- Kernel 3b: output GEMM  out = A.Wo + bias + resid ---------
// m97-style global_load_lds staging (linear pitch-32 LDS); round-3
// scattered epilogue (block-local full lines -> L2 write-combines).
__global__ __launch_bounds__(256, 2) void gemm_kernel(const bf16* __restrict__ A,
                                                      const bf16* __restrict__ W,
                                                      const void* __restrict__ bias,
                                                      const void* __restrict__ resid,
                                                      void* __restrict__ out,
                                                      const int* __restrict__ flag) {
    __shared__ bf16 As[128 * 32];
    __shared__ bf16 Bs[128 * 32];
    int f  = *flag;
    int m0 = blockIdx.x * 128;
    int n0 = blockIdx.y * 128;
    int tid  = threadIdx.x;
    int lane = tid & 63;
    int wave = tid >> 6;
    int wm = (wave & 1) * 64;
    int wn = (wave >> 1) * 64;
    int l15  = lane & 15;
    int quad = lane >> 4;
    int wrow = lane >> 2;
    int wcol = (lane & 3) * 8;

    f32x4 acc[4][4] = {};
    for (int k0 = 0; k0 < C_DIM; k0 += 32) {
        __syncthreads();
#pragma unroll
        for (int j = 0; j < 2; ++j) {
            int rowb = (j * 4 + wave) * 16;
            async_ld16(&A[(size_t)(m0 + rowb + wrow) * C_DIM + k0 + wcol], &As[rowb * 32]);
            async_ld16(&W[(size_t)(n0 + rowb + wrow) * C_DIM + k0 + wcol], &Bs[rowb * 32]);
        }
        __syncthreads();
        bf16x8 af[4], bfr[4];
#pragma unroll
        for (int i = 0; i < 4; ++i)
            af[i] = *(bf16x8*)&As[(wm + i * 16 + l15) * 32 + quad * 8];
#pragma unroll
        for (int j = 0; j < 4; ++j)
            bfr[j] = *(bf16x8*)&Bs[(wn + j * 16 + l15) * 32 + quad * 8];
#pragma unroll
        for (int i = 0; i < 4; ++i)
#pragma unroll
            for (int j = 0; j < 4; ++j)
                acc[i][j] = __builtin_amdgcn_mfma_f32_16x16x32_bf16(af[i], bfr[j], acc[i][j], 0, 0, 0);
    }
    if (f) {
        bf16* op = (bf16*)out;
        const bf16* rp = (const bf16*)resid;
#pragma unroll
        for (int i = 0; i < 4; ++i)
#pragma unroll
            for (int j = 0; j < 4; ++j)
#pragma unroll
                for (int rg = 0; rg < 4; ++rg) {
                    int m = m0 + wm + i * 16 + quad * 4 + rg;
                    int n = n0 + wn + j * 16 + l15;
                    float bv = (float)((const bf16*)bias)[n];
                    int b = m >> 13, s = m & 8191;
                    size_t idx = ((size_t)b * C_DIM + n) * S_DIM + s;
                    op[idx] = (bf16)(acc[i][j][rg] + bv + (float)rp[idx]);
                }
    } else {
        float* op = (float*)out;
        const float* rp = (const float*)resid;
#pragma unroll
        for (int i = 0; i < 4; ++i)
#pragma unroll
            for (int j = 0; j < 4; ++j)
#pragma unroll
                for (int rg = 0; rg < 4; ++rg) {
                    int m = m0 + wm + i * 16 + quad * 4 + rg;
                    int n = n0 + wn + j * 16 + l15;
                    float bv = ((const float*)bias)[n];
                    int b = m >> 13, s = m & 8191;
                    size_t idx = ((size_t)b * C_DIM + n) * S_DIM + s;
                    op[idx] = acc[i][j][rg] + bv + rp[idx];
                }
    }
}

// ------------- Kernel 4a: balanced split flash attention -----------------
// r8 config (best measured): 512 blocks x 72 chunks, paired-b128 K/V
// reads, XCD-chunked swizzle, s_setprio around MFMA clusters, 4-chain QK.
__global__ __launch_bounds__(256, 2) void attn_split_kernel(const unsigned char* __restrict__ q,
                                                            const unsigned char* __restrict__ k,
                                                            const unsigned char* __restrict__ vt,
                                                            bf16* __restrict__ part,
                                                            float* __restrict__ lsum,
                                                            int* __restrict__ counter,
                                                            int* __restrict__ cnt,
                                                            int* __restrict__ slist) {
    __shared__ unsigned char Ks[2][16384];   // 32 KB
    __shared__ unsigned char Vs[2][16384];   // 32 KB
    __shared__ unsigned char Ps[4][16 * 40]; // 2.5 KB
    __shared__ int slot_sh;
    int tid  = threadIdx.x;
    int lane = tid & 63;
    int wave = tid >> 6;
    int l15  = lane & 15;
    int quad = lane >> 4;

    // ---- XCD-chunked swizzle: consecutive virtual ids land on one XCD ----
    int bid = blockIdx.x;
    int vb  = (bid & 7) * 64 + (bid >> 3);   // 512 = 8 XCDs x 64 chunks, bijective
    int g0 = vb * 72;
    int b_ = (g0 >= 18432) ? 1 : 0;
    int r  = g0 - b_ * 18432;
    int f_ = 0;
    while (r >= 256 * (f_ + 1) * (f_ + 2)) ++f_;
    int L   = 32 * (f_ + 1);
    int rr  = r - 256 * f_ * (f_ + 1);
    int tif = rr / L;
    int cw  = rr - tif * L;

    // ---- Q fragments for current tile (16 K-steps over C=512) ----
    long qf[16];
    {
        int qbase = (f_ * 16 + tif) * 64 + wave * 16;
        const unsigned char* qp = q + (size_t)(b_ * S_DIM + qbase + l15) * C_DIM;
#pragma unroll
        for (int ks = 0; ks < 16; ++ks)
            qf[ks] = *(const long*)&qp[ks * 32 + quad * 8];
    }

    f32x4 oacc[32] = {};
    float l_i[4] = {0.f, 0.f, 0.f, 0.f};
    const float scale = 0.044194173824159216f;  // 1/sqrt(512)

    // prefetch chunk 0 into buffer 0 (wave-uniform LDS base + lane*16)
    {
        const unsigned char* ka = k  + ((size_t)(b_ * 256 + cw) << 14);
        const unsigned char* va = vt + ((size_t)(b_ * 256 + cw) << 14);
#pragma unroll
        for (int j = 0; j < 4; ++j) {
            int base = (j * 4 + wave) * 1024;
            async_ld16(ka + base + lane * 16, &Ks[0][base]);
            async_ld16(va + base + lane * 16, &Vs[0][base]);
        }
    }
    __syncthreads();

    for (int i = 0; i < 72; ++i) {
        int last = (i == 71);
        int nb = b_, nf = f_, nL = L, ntif = tif, ncw = cw + 1;
        int newtile = 0;
        if (ncw == L) {
            ncw = 0; newtile = 1; ntif = tif + 1;
            if (ntif == 16) {
                ntif = 0; nf = f_ + 1; nL = L + 32;
                if (nf == 8) { nf = 0; nL = 32; nb = b_ + 1; }
            }
        }
        if (last) { nb = b_; nf = f_; nL = L; ntif = tif; ncw = cw; newtile = 0; }

        // ---- prefetch next chunk into the other buffer ----
        {
            const unsigned char* ka = k  + ((size_t)(nb * 256 + ncw) << 14);
            const unsigned char* va = vt + ((size_t)(nb * 256 + ncw) << 14);
            unsigned char* kd = Ks[(i + 1) & 1];
            unsigned char* vd = Vs[(i + 1) & 1];
#pragma unroll
            for (int j = 0; j < 4; ++j) {
                int base = (j * 4 + wave) * 1024;
                async_ld16(ka + base + lane * 16, kd + base);
                async_ld16(va + base + lane * 16, vd + base);
            }
        }
        const unsigned char* kb = Ks[i & 1];
        const unsigned char* vb2 = Vs[i & 1];

        // S = q . k^T : paired b128 reads, 4 independent 8-deep chains
        f32x4 sa[2] = {}, sb[2] = {};
        __builtin_amdgcn_s_setprio(1);
#pragma unroll
        for (int pp = 0; pp < 4; ++pp) {
#pragma unroll
            for (int nt = 0; nt < 2; ++nt) {
                longx2 ka2 = *(const longx2*)&kb[(((pp * 4 + quad) * 32) + nt * 16 + l15) * 16];
                longx2 kb2 = *(const longx2*)&kb[((((pp + 4) * 4 + quad) * 32) + nt * 16 + l15) * 16];
                sa[nt] = __builtin_amdgcn_mfma_f32_16x16x32_fp8_fp8(qf[2 * pp],     ka2[0], sa[nt], 0, 0, 0);
                sb[nt] = __builtin_amdgcn_mfma_f32_16x16x32_fp8_fp8(qf[2 * pp + 8], kb2[0], sb[nt], 0, 0, 0);
                sa[nt] = __builtin_amdgcn_mfma_f32_16x16x32_fp8_fp8(qf[2 * pp + 1], ka2[1], sa[nt], 0, 0, 0);
                sb[nt] = __builtin_amdgcn_mfma_f32_16x16x32_fp8_fp8(qf[2 * pp + 9], kb2[1], sb[nt], 0, 0, 0);
            }
        }
        __builtin_amdgcn_s_setprio(0);
        // softmax-lite: raw exp (scores bounded), per-lane l accumulation
        float p0[4], p1[4];
#pragma unroll
        for (int rg = 0; rg < 4; ++rg) {
            p0[rg] = __expf((sa[0][rg] + sb[0][rg]) * scale);
            p1[rg] = __expf((sa[1][rg] + sb[1][rg]) * scale);
            l_i[rg] += p0[rg] + p1[rg];
        }
        // P (C layout) -> per-wave fp8 LDS scratch -> A layout (same-wave)
        unsigned char* pw = Ps[wave];
#pragma unroll
        for (int rg = 0; rg < 4; ++rg) {
            pw[(quad * 4 + rg) * 40 + l15] = to_fp8(p0[rg]);
            pw[(quad * 4 + rg) * 40 + 16 + l15] = to_fp8(p1[rg]);
        }
        long pf = *(const long*)&pw[l15 * 40 + quad * 8];
        // PV: paired b128 reads = 2 dn per load
        __builtin_amdgcn_s_setprio(1);
#pragma unroll
        for (int dnp = 0; dnp < 16; ++dnp) {
            longx2 vf = *(const longx2*)&vb2[quad * 4096 + (dnp * 16 + l15) * 16];
            oacc[2 * dnp]     = __builtin_amdgcn_mfma_f32_16x16x32_fp8_fp8(pf, vf[0], oacc[2 * dnp], 0, 0, 0);
            oacc[2 * dnp + 1] = __builtin_amdgcn_mfma_f32_16x16x32_fp8_fp8(pf, vf[1], oacc[2 * dnp + 1], 0, 0, 0);
        }
        __builtin_amdgcn_s_setprio(0);

        // ---- flush segment at tile boundary / end of span ----
        if (last || newtile) {
            int ord = b_ * 128 + f_ * 16 + tif;   // q-tile ordinal 0..255
            if (tid == 0) {
                int s = atomicAdd(counter, 1);
                int pos = atomicAdd(&cnt[ord], 1);
                slist[ord * 8 + pos] = s;
                slot_sh = s;
            }
            __syncthreads();
            int slot = slot_sh;
#pragma unroll
            for (int rg = 0; rg < 4; ++rg)
                for (int d = 1; d < 16; d <<= 1)
                    l_i[rg] += __shfl_xor(l_i[rg], d);
            float rinv[4];
#pragma unroll
            for (int rg = 0; rg < 4; ++rg) rinv[rg] = 1.f / l_i[rg];
            bf16* pp2 = part + ((size_t)slot * 64 + wave * 16) * C_DIM;
#pragma unroll
            for (int dn = 0; dn < 32; ++dn)
#pragma unroll
                for (int rg = 0; rg < 4; ++rg)
                    pp2[(size_t)(quad * 4 + rg) * C_DIM + dn * 16 + l15] =
                        (bf16)(oacc[dn][rg] * rinv[rg]);
            if (l15 == 0) {
#pragma unroll
                for (int rg = 0; rg < 4; ++rg)
                    lsum[slot * 64 + wave * 16 + quad * 4 + rg] = l_i[rg];
            }
            if (!last) {
#pragma unroll
                for (int dn = 0; dn < 32; ++dn) oacc[dn] = (f32x4){0.f, 0.f, 0.f, 0.f};
#pragma unroll
                for (int rg = 0; rg < 4; ++rg) l_i[rg] = 0.f;
                int nqbase = (nf * 16 + ntif) * 64 + wave * 16;
                const unsigned char* qp = q + (size_t)(nb * S_DIM + nqbase + l15) * C_DIM;
#pragma unroll
                for (int ks = 0; ks < 16; ++ks)
                    qf[ks] = *(const long*)&qp[ks * 32 + quad * 8];
            }
        }
        b_ = nb; f_ = nf; L = nL; tif = ntif; cw = ncw;
        __syncthreads();   // drains prefetch + all waves done with buffers
    }
}

// ------------- Kernel 4b: non-split fallback flash attention -------------
__global__ __launch_bounds__(256, 2) void attn_kernel(const unsigned char* __restrict__ q,
                                                      const unsigned char* __restrict__ k,
                                                      const unsigned char* __restrict__ vt,
                                                      bf16* __restrict__ ob) {
    __shared__ unsigned char Ks[2][16384];
    __shared__ unsigned char Vs[2][16384];
    __shared__ unsigned char Ps[4][16 * 40];
    int id = blockIdx.x;
    int b = id >> 7;
    int t = id & 127;
    int q0 = t * 64;
    int kc1 = ((t >> 4) + 1) << 10;
    int tid  = threadIdx.x;
    int lane = tid & 63;
    int wave = tid >> 6;
    int l15  = lane & 15;
    int quad = lane >> 4;
    int qbase = q0 + wave * 16;
    int nchunks = kc1 >> 5;

    long qf[16];
    const unsigned char* qp = q + (size_t)(b * S_DIM + qbase + l15) * C_DIM;
#pragma unroll
    for (int ks = 0; ks < 16; ++ks)
        qf[ks] = *(const long*)&qp[ks * 32 + quad * 8];

    f32x4 oacc[32] = {};
    float l_i[4] = {0.f, 0.f, 0.f, 0.f};
    const float scale = 0.044194173824159216f;

    const unsigned char* kbase = k  + ((size_t)(b * 256) << 14);
    const unsigned char* vbase = vt + ((size_t)(b * 256) << 14);

#pragma unroll
    for (int j = 0; j < 4; ++j) {
        int base = (j * 4 + wave) * 1024;
        async_ld16(kbase + base + lane * 16, &Ks[0][base]);
        async_ld16(vbase + base + lane * 16, &Vs[0][base]);
    }
    __syncthreads();

    for (int p = 0; p < nchunks; ++p) {
        int pn = (p + 1 < nchunks) ? (p + 1) : p;
        const unsigned char* ksub = kbase + ((size_t)pn << 14);
        const unsigned char* vsub = vbase + ((size_t)pn << 14);
        unsigned char* kd = Ks[(p + 1) & 1];
        unsigned char* vd = Vs[(p + 1) & 1];
#pragma unroll
        for (int j = 0; j < 4; ++j) {
            int base = (j * 4 + wave) * 1024;
            async_ld16(ksub + base + lane * 16, kd + base);
            async_ld16(vsub + base + lane * 16, vd + base);
        }
        const unsigned char* kb = Ks[p & 1];
        const unsigned char* vb = Vs[p & 1];
        f32x4 st[2] = {};
#pragma unroll
        for (int nt = 0; nt < 2; ++nt) {
#pragma unroll
            for (int pp = 0; pp < 8; ++pp) {
                longx2 kf = *(const longx2*)&kb[(((pp * 4 + quad) * 32) + nt * 16 + l15) * 16];
                st[nt] = __builtin_amdgcn_mfma_f32_16x16x32_fp8_fp8(qf[2 * pp], kf[0], st[nt], 0, 0, 0);
                st[nt] = __builtin_amdgcn_mfma_f32_16x16x32_fp8_fp8(qf[2 * pp + 1], kf[1], st[nt], 0, 0, 0);
            }
        }
        float p0[4], p1[4];
#pragma unroll
        for (int rg = 0; rg < 4; ++rg) {
            p0[rg] = __expf(st[0][rg] * scale);
            p1[rg] = __expf(st[1][rg] * scale);
            l_i[rg] += p0[rg] + p1[rg];
        }
        unsigned char* pw = Ps[wave];
#pragma unroll
        for (int rg = 0; rg < 4; ++rg) {
            pw[(quad * 4 + rg) * 40 + l15] = to_fp8(p0[rg]);
            pw[(quad * 4 + rg) * 40 + 16 + l15] = to_fp8(p1[rg]);
        }
        long pf = *(const long*)&pw[l15 * 40 + quad * 8];
#pragma unroll
        for (int dnp = 0; dnp < 16; ++dnp) {
            longx2 vf = *(const longx2*)&vb[quad * 4096 + (dnp * 16 + l15) * 16];
            oacc[2 * dnp]     = __builtin_amdgcn_mfma_f32_16x16x32_fp8_fp8(pf, vf[0], oacc[2 * dnp], 0, 0, 0);
            oacc[2 * dnp + 1] = __builtin_amdgcn_mfma_f32_16x16x32_fp8_fp8(pf, vf[1], oacc[2 * dnp + 1], 0, 0, 0);
        }
        __syncthreads();
    }
#pragma unroll
    for (int rg = 0; rg < 4; ++rg)
        for (int d = 1; d < 16; d <<= 1)
            l_i[rg] += __shfl_xor(l_i[rg], d);
    float rinv[4];
#pragma unroll
    for (int rg = 0; rg < 4; ++rg) rinv[rg] = 1.f / l_i[rg];
    bf16* op = ob + (size_t)(b * S_DIM + qbase) * C_DIM;
#pragma unroll
    for (int dn = 0; dn < 32; ++dn)
#pragma unroll
        for (int rg = 0; rg < 4; ++rg)
            op[(size_t)(quad * 4 + rg) * C_DIM + dn * 16 + l15] =
                (bf16)(oacc[dn][rg] * rinv[rg]);
}

// ------------- Kernel 5: split-K combine (slot-list weighted sum) --------
// grid 256 x 4: blockIdx.y selects a 128-channel quarter.
__global__ __launch_bounds__(256) void combine_kernel(const bf16* __restrict__ part,
                                                      const float* __restrict__ lsum,
                                                      bf16* __restrict__ ob,
                                                      const int* __restrict__ cnt,
                                                      const int* __restrict__ slist) {
    int id = blockIdx.x;            // q-tile ordinal 0..255
    int b  = id >> 7;
    int q0 = (id & 127) * 64;
    int U  = cnt[id];               // 1..~5 segments
    int qq = threadIdx.x >> 2;      // 0..63
    int cr = threadIdx.x & 3;       // 32-ch sub-segment
    int cbase = blockIdx.y * 128 + cr * 32;
    int sl[8];
    float w[8];
    float D = 0.f;
    for (int u = 0; u < U; ++u) {
        sl[u] = slist[id * 8 + u];
        w[u] = lsum[sl[u] * 64 + qq];
        D += w[u];
    }
    float Dinv = 1.f / D;
    for (int u = 0; u < U; ++u) w[u] *= Dinv;
    bf16* op = ob + (size_t)(b * S_DIM + q0 + qq) * C_DIM + cbase;
    for (int ch = 0; ch < 4; ++ch) {
        float acc[8] = {};
        for (int u = 0; u < U; ++u) {
            bf16x8 pv = *(const bf16x8*)&part[((size_t)sl[u] * 64 + qq) * C_DIM + cbase + ch * 8];
#pragma unroll
            for (int j = 0; j < 8; ++j) acc[j] += w[u] * (float)pv[j];
        }
        bf16x8 o8;
#pragma unroll
        for (int j = 0; j < 8; ++j) o8[j] = (bf16)acc[j];
        *(bf16x8*)&op[ch * 8] = o8;
    }
}

extern "C" void kernel_launch(void* const* d_in, const int* in_sizes, int n_in,
                              void* d_out, int out_size, void* d_ws, size_t ws_size,
                              hipStream_t stream) {
    const void* x     = d_in[0];
    const void* gamma = d_in[1];
    const void* wq    = d_in[2];
    const void* bq    = d_in[3];
    const void* wk    = d_in[4];
    const void* bk    = d_in[5];
    const void* wv    = d_in[6];
    const void* bv    = d_in[7];
    const void* wo    = d_in[8];
    const void* bo    = d_in[9];

    char* ws = (char*)d_ws;
    int*   flag    = (int*)ws;                 // [0]=flag, [16]=slot counter, [64..320)=cnt
    int*   counter = (int*)(ws + 64);
    int*   cntp    = (int*)(ws + 256);
    int*   slist   = (int*)(ws + 0x12000);     // 256 q-tiles x 8 slots (8 KB)
    bf16* wqb = (bf16*)(ws + 0x20000);   // 4 weights contiguous, 512 KB each
    bf16* wkb = (bf16*)(ws + 0xA0000);
    bf16* wvb = (bf16*)(ws + 0x120000);
    bf16* wob = (bf16*)(ws + 0x1A0000);
    float* lsum_buf = (float*)(ws + 0x240000);                  // <=768 slots x 64 f32
    bf16* hn  = (bf16*)(ws + 0x400000);                         // 16 MB
    unsigned char* qb  = (unsigned char*)(ws + 0x1400000);      // 8 MB (fp8)
    unsigned char* kb  = (unsigned char*)(ws + 0x1C00000);      // 8 MB
    unsigned char* vtb = (unsigned char*)(ws + 0x2400000);      // 8 MB
    bf16* ob  = (bf16*)(ws + 0x2C00000);                        // 16 MB
    bf16* part = (bf16*)(ws + 0x5400000);                       // <=768 slots x 64 x 512 bf16 (50.3 MB)

    const size_t ws_needed_split = 0x5400000ull + 768ull * 64 * 512 * 2;
    int split = (ws_size >= ws_needed_split) ? 1 : 0;

    hipLaunchKernelGGL(detect_kernel, dim3(1), dim3(64), 0, stream,
                       (const unsigned short*)x, flag);
    hipLaunchKernelGGL(convert_kernel, dim3(1024, 4), dim3(256), 0, stream,
                       wq, wk, wv, wo, wqb, flag);
    hipLaunchKernelGGL(rmshn_kernel, dim3(256), dim3(256), 0, stream, x, gamma, hn, flag);
    hipLaunchKernelGGL(gemm_qkv_kernel, dim3(128, 4), dim3(256), 0, stream,
                       hn, wqb, wkb, wvb, bq, bk, bv, qb, kb, vtb, flag);
    if (split) {
        hipLaunchKernelGGL(attn_split_kernel, dim3(512), dim3(256), 0, stream,
                           qb, kb, vtb, part, lsum_buf, counter, cntp, slist);
        hipLaunchKernelGGL(combine_kernel, dim3(256, 4), dim3(256), 0, stream,
                           part, lsum_buf, ob, cntp, slist);
    } else {
        hipLaunchKernelGGL(attn_kernel, dim3(256), dim3(256), 0, stream, qb, kb, vtb, ob);
    }
    hipLaunchKernelGGL(gemm_kernel, dim3(128, 4), dim3(256), 0, stream, ob, wob, bo, x, d_out, flag);
}

// Round 10
// 344.239 us; speedup vs baseline: 2.2156x; 1.0185x over previous
//
#include <hip/hip_runtime.h>
#include <hip/hip_bf16.h>
#include <math.h>

typedef __bf16 bf16;
typedef __bf16 bf16x8 __attribute__((ext_vector_type(8)));
typedef float f32x4 __attribute__((ext_vector_type(4)));
typedef long longx2 __attribute__((ext_vector_type(2)));

#define C_DIM 512
#define S_DIM 8192

__device__ __forceinline__ void async_ld16(const void* g, void* l) {
    __builtin_amdgcn_global_load_lds(
        (const __attribute__((address_space(1))) unsigned int*)g,
        (__attribute__((address_space(3))) unsigned int*)l, 16, 0, 0);
}

// f32 -> OCP e4m3 via HW cvt (gfx950: v_cvt_pk_fp8_f32 emits OCP format)
__device__ __forceinline__ unsigned char to_fp8(float v) {
    return (unsigned char)(__builtin_amdgcn_cvt_pk_fp8_f32(v, v, 0, false) & 0xFF);
}

// ---------------- Kernel 0: dtype detect (wave ballot) + aux zeroing -----
// flag[0] = dtype flag; flag[16] = slot counter; flag[64..320) = cnt[256]
__global__ void detect_kernel(const unsigned short* __restrict__ xu, int* __restrict__ flag) {
    int j = threadIdx.x;   // 64 threads
    for (int i = 16 + j; i < 320; i += 64) flag[i] = 0;   // zero counter + cnt[256]
    unsigned e = (xu[2 * j] >> 7) & 0xFF;
    unsigned long long m = __ballot(e >= 90 && e <= 140);
    if (j == 0) *flag = (__popcll(m) >= 48) ? 1 : 0;   // 1 = bf16, 0 = fp32
}

// ---------------- Kernel 0b: weights -> bf16 (only needed in fp32 mode) --
__global__ __launch_bounds__(256) void convert_kernel(const void* __restrict__ s0,
                                                      const void* __restrict__ s1,
                                                      const void* __restrict__ s2,
                                                      const void* __restrict__ s3,
                                                      bf16* __restrict__ dst,
                                                      const int* __restrict__ flag) {
    if (*flag) return;   // bf16 inputs: GEMMs read originals directly
    int y = blockIdx.y;
    const void* srcs[4] = {s0, s1, s2, s3};
    const void* src = srcs[y];
    int i = blockIdx.x * 256 + threadIdx.x;
    bf16* d = dst + (size_t)y * 262144;
    volatile const float* s = (volatile const float*)src;
    d[i] = (bf16)s[i];
}

// ------------- Kernel 1+2 fused: RMS norm + transpose -> hn[b][s][c] -----
// 32-token blocks, grid 512 -> 2 blocks/CU (8 waves; was 1 block/4 waves).
// Same algorithm as r8's 64-token version, halved LDS (~36 KB).
__global__ __launch_bounds__(256, 2) void rmshn_kernel(const void* __restrict__ x,
                                                       const void* __restrict__ gamma,
                                                       bf16* __restrict__ hn,
                                                       const int* __restrict__ flag) {
    __shared__ unsigned short Xs[512][34];   // 34.8 KB; read bank-stride 17 dw (2-way, free)
    __shared__ float red[8][32];
    __shared__ float rbuf[32];
    int f  = *flag;
    int b  = blockIdx.x >> 8;
    int s0 = (blockIdx.x & 255) * 32;
    int col32 = threadIdx.x & 31;
    int rowc  = threadIdx.x >> 5;   // 0..7
    float acc = 0.f;
    if (f) {
        const unsigned short* xp = (const unsigned short*)x + (size_t)b * C_DIM * S_DIM + s0 + col32;
#pragma unroll 8
        for (int it = 0; it < 64; ++it) {
            int c = it * 8 + rowc;
            unsigned short u = xp[(size_t)c * S_DIM];
            float v = __uint_as_float(((unsigned int)u) << 16);
            acc += v * v;
            Xs[c][col32] = u;
        }
    } else {
        const float* xp = (const float*)x + (size_t)b * C_DIM * S_DIM + s0 + col32;
#pragma unroll 8
        for (int it = 0; it < 64; ++it) {
            int c = it * 8 + rowc;
            float v = xp[(size_t)c * S_DIM];
            acc += v * v;
            bf16 h = (bf16)v;
            Xs[c][col32] = *(unsigned short*)&h;
        }
    }
    red[rowc][col32] = acc;
    __syncthreads();
    if (rowc == 0) {
        float t = 0.f;
#pragma unroll
        for (int r = 0; r < 8; ++r) t += red[r][col32];
        rbuf[col32] = 22.627416997969522f / fmaxf(sqrtf(t), 1e-12f);
    }
    __syncthreads();
    int col64 = threadIdx.x & 63;
    int row4  = threadIdx.x >> 6;   // 0..3
    bf16* hp = hn + ((size_t)b * S_DIM + s0) * C_DIM;
    for (int cq = 0; cq < 8; ++cq) {
        int c = cq * 64 + col64;
        float g = f ? (float)((const bf16*)gamma)[c] : ((const float*)gamma)[c];
#pragma unroll
        for (int i = 0; i < 8; ++i) {
            int s_l = row4 + i * 4;   // 0..31
            float v = __uint_as_float(((unsigned int)Xs[c][s_l]) << 16);
            hp[(size_t)s_l * C_DIM + c] = (bf16)(v * rbuf[s_l] * g);
        }
    }
}

// ------------- Kernel 3a: fused QKV GEMM --------------------------------
// m97-style global_load_lds staging; V epilogue packs 4 fp8 into one dword
// store (rg=0..3 are consecutive bytes of one 8B V unit; chunk/kq/pair
// bits constant across rg -> single aligned u32 store).
__global__ __launch_bounds__(256, 2) void gemm_qkv_kernel(const bf16* __restrict__ A,
                                                          const bf16* __restrict__ Wqc,
                                                          const bf16* __restrict__ Wkc,
                                                          const bf16* __restrict__ Wvc,
                                                          const void* __restrict__ wqo,
                                                          const void* __restrict__ wko,
                                                          const void* __restrict__ wvo,
                                                          const void* __restrict__ bq,
                                                          const void* __restrict__ bk,
                                                          const void* __restrict__ bv,
                                                          unsigned char* __restrict__ oq,
                                                          unsigned char* __restrict__ ok,
                                                          unsigned char* __restrict__ ov,
                                                          const int* __restrict__ flag) {
    __shared__ bf16 As [128 * 32];   // 8 KB each, linear 64-B rows
    __shared__ bf16 Bqs[128 * 32];
    __shared__ bf16 Bks[128 * 32];
    __shared__ bf16 Bvs[128 * 32];
    int f  = *flag;
    const bf16* Wq = f ? (const bf16*)wqo : Wqc;
    const bf16* Wk = f ? (const bf16*)wko : Wkc;
    const bf16* Wv = f ? (const bf16*)wvo : Wvc;
    int m0 = blockIdx.x * 128;
    int n0 = blockIdx.y * 128;
    int tid  = threadIdx.x;
    int lane = tid & 63;
    int wave = tid >> 6;
    int wm = (wave & 1) * 64;
    int wn = (wave >> 1) * 64;
    int l15  = lane & 15;
    int quad = lane >> 4;
    int wrow = lane >> 2;          // 0..15: row within 16-row slab
    int wcol = (lane & 3) * 8;     // 0/8/16/24: element quarter

    f32x4 aq[4][4] = {}, ak[4][4] = {}, av[4][4] = {};
    for (int k0 = 0; k0 < C_DIM; k0 += 32) {
        __syncthreads();
#pragma unroll
        for (int j = 0; j < 2; ++j) {
            int rowb = (j * 4 + wave) * 16;
            async_ld16(&A [(size_t)(m0 + rowb + wrow) * C_DIM + k0 + wcol], &As [rowb * 32]);
            async_ld16(&Wq[(size_t)(n0 + rowb + wrow) * C_DIM + k0 + wcol], &Bqs[rowb * 32]);
            async_ld16(&Wk[(size_t)(n0 + rowb + wrow) * C_DIM + k0 + wcol], &Bks[rowb * 32]);
            async_ld16(&Wv[(size_t)(n0 + rowb + wrow) * C_DIM + k0 + wcol], &Bvs[rowb * 32]);
        }
        __syncthreads();   // drains vmcnt -> staged data visible
        bf16x8 af[4];
#pragma unroll
        for (int i = 0; i < 4; ++i)
            af[i] = *(bf16x8*)&As[(wm + i * 16 + l15) * 32 + quad * 8];
#pragma unroll
        for (int j = 0; j < 4; ++j) {
            int boff = (wn + j * 16 + l15) * 32 + quad * 8;
            bf16x8 b0 = *(bf16x8*)&Bqs[boff];
#pragma unroll
            for (int i = 0; i < 4; ++i)
                aq[i][j] = __builtin_amdgcn_mfma_f32_16x16x32_bf16(af[i], b0, aq[i][j], 0, 0, 0);
            bf16x8 b1 = *(bf16x8*)&Bks[boff];
#pragma unroll
            for (int i = 0; i < 4; ++i)
                ak[i][j] = __builtin_amdgcn_mfma_f32_16x16x32_bf16(af[i], b1, ak[i][j], 0, 0, 0);
            bf16x8 b2 = *(bf16x8*)&Bvs[boff];
#pragma unroll
            for (int i = 0; i < 4; ++i)
                av[i][j] = __builtin_amdgcn_mfma_f32_16x16x32_bf16(af[i], b2, av[i][j], 0, 0, 0);
        }
    }
#pragma unroll
    for (int i = 0; i < 4; ++i)
#pragma unroll
        for (int j = 0; j < 4; ++j) {
            int n = n0 + wn + j * 16 + l15;
            float bvq = f ? (float)((const bf16*)bq)[n] : ((const float*)bq)[n];
            float bvk = f ? (float)((const bf16*)bk)[n] : ((const float*)bk)[n];
            float bvv = f ? (float)((const bf16*)bv)[n] : ((const float*)bv)[n];
            // q + K: byte stores (channel is the contiguous axis -> across lanes)
#pragma unroll
            for (int rg = 0; rg < 4; ++rg) {
                int m = m0 + wm + i * 16 + quad * 4 + rg;
                oq[(size_t)m * C_DIM + n] = to_fp8(aq[i][j][rg] + bvq);
                size_t ik = (size_t)(m >> 5) * 16384 +
                            (((size_t)(n >> 6) * 4 + ((n >> 3) & 3)) * 32 + (m & 31)) * 16 +
                            ((n >> 5) & 1) * 8 + (n & 7);
                ok[ik] = to_fp8(ak[i][j][rg] + bvk);
            }
            // V: key is the contiguous byte axis; rg = 4 consecutive keys -> one u32
            {
                int mb = m0 + wm + i * 16 + quad * 4;   // rg = 0 key
                unsigned vpack = 0;
#pragma unroll
                for (int rg = 0; rg < 4; ++rg)
                    vpack |= (unsigned)to_fp8(av[i][j][rg] + bvv) << (8 * rg);
                size_t iv = (size_t)(mb >> 5) * 16384 + ((size_t)(mb >> 3) & 3) * 4096 +
                            (((size_t)(n >> 5) * 16 + (n & 15)) * 2 + ((n >> 4) & 1)) * 8 + (mb & 7);
                *(unsigned*)&ov[iv] = vpack;
            }
        }
}

// ------------- Kernel 3b: output GEMM  out = A.Wo + bias + resid ---------
__global__ __launch_bounds__(256, 2) void gemm_kernel(const bf16* __restrict__ A,
                                                      const bf16* __restrict__ Wc,
                                                      const void* __restrict__ wo_orig,
                                                      const void* __restrict__ bias,
                                                      const void* __restrict__ resid,
                                                      void* __restrict__ out,
                                                      const int* __restrict__ flag) {
    __shared__ bf16 As[128 * 32];
    __shared__ bf16 Bs[128 * 32];
    int f  = *flag;
    const bf16* W = f ? (const bf16*)wo_orig : Wc;
    int m0 = blockIdx.x * 128;
    int n0 = blockIdx.y * 128;
    int tid  = threadIdx.x;
    int lane = tid & 63;
    int wave = tid >> 6;
    int wm = (wave & 1) * 64;
    int wn = (wave >> 1) * 64;
    int l15  = lane & 15;
    int quad = lane >> 4;
    int wrow = lane >> 2;
    int wcol = (lane & 3) * 8;

    f32x4 acc[4][4] = {};
    for (int k0 = 0; k0 < C_DIM; k0 += 32) {
        __syncthreads();
#pragma unroll
        for (int j = 0; j < 2; ++j) {
            int rowb = (j * 4 + wave) * 16;
            async_ld16(&A[(size_t)(m0 + rowb + wrow) * C_DIM + k0 + wcol], &As[rowb * 32]);
            async_ld16(&W[(size_t)(n0 + rowb + wrow) * C_DIM + k0 + wcol], &Bs[rowb * 32]);
        }
        __syncthreads();
        bf16x8 af[4], bfr[4];
#pragma unroll
        for (int i = 0; i < 4; ++i)
            af[i] = *(bf16x8*)&As[(wm + i * 16 + l15) * 32 + quad * 8];
#pragma unroll
        for (int j = 0; j < 4; ++j)
            bfr[j] = *(bf16x8*)&Bs[(wn + j * 16 + l15) * 32 + quad * 8];
#pragma unroll
        for (int i = 0; i < 4; ++i)
#pragma unroll
            for (int j = 0; j < 4; ++j)
                acc[i][j] = __builtin_amdgcn_mfma_f32_16x16x32_bf16(af[i], bfr[j], acc[i][j], 0, 0, 0);
    }
    if (f) {
        bf16* op = (bf16*)out;
        const bf16* rp = (const bf16*)resid;
#pragma unroll
        for (int i = 0; i < 4; ++i)
#pragma unroll
            for (int j = 0; j < 4; ++j)
#pragma unroll
                for (int rg = 0; rg < 4; ++rg) {
                    int m = m0 + wm + i * 16 + quad * 4 + rg;
                    int n = n0 + wn + j * 16 + l15;
                    float bv = (float)((const bf16*)bias)[n];
                    int b = m >> 13, s = m & 8191;
                    size_t idx = ((size_t)b * C_DIM + n) * S_DIM + s;
                    op[idx] = (bf16)(acc[i][j][rg] + bv + (float)rp[idx]);
                }
    } else {
        float* op = (float*)out;
        const float* rp = (const float*)resid;
#pragma unroll
        for (int i = 0; i < 4; ++i)
#pragma unroll
            for (int j = 0; j < 4; ++j)
#pragma unroll
                for (int rg = 0; rg < 4; ++rg) {
                    int m = m0 + wm + i * 16 + quad * 4 + rg;
                    int n = n0 + wn + j * 16 + l15;
                    float bv = ((const float*)bias)[n];
                    int b = m >> 13, s = m & 8191;
                    size_t idx = ((size_t)b * C_DIM + n) * S_DIM + s;
                    op[idx] = acc[i][j][rg] + bv + rp[idx];
                }
    }
}

// ------------- Kernel 4a: balanced split flash attention -----------------
// r8/r9 best config (unchanged): 512 blocks x 72 chunks, paired-b128 K/V
// reads, XCD-chunked swizzle, s_setprio around MFMA clusters, 4-chain QK.
__global__ __launch_bounds__(256, 2) void attn_split_kernel(const unsigned char* __restrict__ q,
                                                            const unsigned char* __restrict__ k,
                                                            const unsigned char* __restrict__ vt,
                                                            bf16* __restrict__ part,
                                                            float* __restrict__ lsum,
                                                            int* __restrict__ counter,
                                                            int* __restrict__ cnt,
                                                            int* __restrict__ slist) {
    __shared__ unsigned char Ks[2][16384];   // 32 KB
    __shared__ unsigned char Vs[2][16384];   // 32 KB
    __shared__ unsigned char Ps[4][16 * 40]; // 2.5 KB
    __shared__ int slot_sh;
    int tid  = threadIdx.x;
    int lane = tid & 63;
    int wave = tid >> 6;
    int l15  = lane & 15;
    int quad = lane >> 4;

    // ---- XCD-chunked swizzle: consecutive virtual ids land on one XCD ----
    int bid = blockIdx.x;
    int vb  = (bid & 7) * 64 + (bid >> 3);   // 512 = 8 XCDs x 64 chunks, bijective
    int g0 = vb * 72;
    int b_ = (g0 >= 18432) ? 1 : 0;
    int r  = g0 - b_ * 18432;
    int f_ = 0;
    while (r >= 256 * (f_ + 1) * (f_ + 2)) ++f_;
    int L   = 32 * (f_ + 1);
    int rr  = r - 256 * f_ * (f_ + 1);
    int tif = rr / L;
    int cw  = rr - tif * L;

    // ---- Q fragments for current tile (16 K-steps over C=512) ----
    long qf[16];
    {
        int qbase = (f_ * 16 + tif) * 64 + wave * 16;
        const unsigned char* qp = q + (size_t)(b_ * S_DIM + qbase + l15) * C_DIM;
#pragma unroll
        for (int ks = 0; ks < 16; ++ks)
            qf[ks] = *(const long*)&qp[ks * 32 + quad * 8];
    }

    f32x4 oacc[32] = {};
    float l_i[4] = {0.f, 0.f, 0.f, 0.f};
    const float scale = 0.044194173824159216f;  // 1/sqrt(512)

    // prefetch chunk 0 into buffer 0 (wave-uniform LDS base + lane*16)
    {
        const unsigned char* ka = k  + ((size_t)(b_ * 256 + cw) << 14);
        const unsigned char* va = vt + ((size_t)(b_ * 256 + cw) << 14);
#pragma unroll
        for (int j = 0; j < 4; ++j) {
            int base = (j * 4 + wave) * 1024;
            async_ld16(ka + base + lane * 16, &Ks[0][base]);
            async_ld16(va + base + lane * 16, &Vs[0][base]);
        }
    }
    __syncthreads();

    for (int i = 0; i < 72; ++i) {
        int last = (i == 71);
        int nb = b_, nf = f_, nL = L, ntif = tif, ncw = cw + 1;
        int newtile = 0;
        if (ncw == L) {
            ncw = 0; newtile = 1; ntif = tif + 1;
            if (ntif == 16) {
                ntif = 0; nf = f_ + 1; nL = L + 32;
                if (nf == 8) { nf = 0; nL = 32; nb = b_ + 1; }
            }
        }
        if (last) { nb = b_; nf = f_; nL = L; ntif = tif; ncw = cw; newtile = 0; }

        // ---- prefetch next chunk into the other buffer ----
        {
            const unsigned char* ka = k  + ((size_t)(nb * 256 + ncw) << 14);
            const unsigned char* va = vt + ((size_t)(nb * 256 + ncw) << 14);
            unsigned char* kd = Ks[(i + 1) & 1];
            unsigned char* vd = Vs[(i + 1) & 1];
#pragma unroll
            for (int j = 0; j < 4; ++j) {
                int base = (j * 4 + wave) * 1024;
                async_ld16(ka + base + lane * 16, kd + base);
                async_ld16(va + base + lane * 16, vd + base);
            }
        }
        const unsigned char* kb = Ks[i & 1];
        const unsigned char* vb2 = Vs[i & 1];

        // S = q . k^T : paired b128 reads, 4 independent 8-deep chains
        f32x4 sa[2] = {}, sb[2] = {};
        __builtin_amdgcn_s_setprio(1);
#pragma unroll
        for (int pp = 0; pp < 4; ++pp) {
#pragma unroll
            for (int nt = 0; nt < 2; ++nt) {
                longx2 ka2 = *(const longx2*)&kb[(((pp * 4 + quad) * 32) + nt * 16 + l15) * 16];
                longx2 kb2 = *(const longx2*)&kb[((((pp + 4) * 4 + quad) * 32) + nt * 16 + l15) * 16];
                sa[nt] = __builtin_amdgcn_mfma_f32_16x16x32_fp8_fp8(qf[2 * pp],     ka2[0], sa[nt], 0, 0, 0);
                sb[nt] = __builtin_amdgcn_mfma_f32_16x16x32_fp8_fp8(qf[2 * pp + 8], kb2[0], sb[nt], 0, 0, 0);
                sa[nt] = __builtin_amdgcn_mfma_f32_16x16x32_fp8_fp8(qf[2 * pp + 1], ka2[1], sa[nt], 0, 0, 0);
                sb[nt] = __builtin_amdgcn_mfma_f32_16x16x32_fp8_fp8(qf[2 * pp + 9], kb2[1], sb[nt], 0, 0, 0);
            }
        }
        __builtin_amdgcn_s_setprio(0);
        // softmax-lite: raw exp (scores bounded), per-lane l accumulation
        float p0[4], p1[4];
#pragma unroll
        for (int rg = 0; rg < 4; ++rg) {
            p0[rg] = __expf((sa[0][rg] + sb[0][rg]) * scale);
            p1[rg] = __expf((sa[1][rg] + sb[1][rg]) * scale);
            l_i[rg] += p0[rg] + p1[rg];
        }
        // P (C layout) -> per-wave fp8 LDS scratch -> A layout (same-wave)
        unsigned char* pw = Ps[wave];
#pragma unroll
        for (int rg = 0; rg < 4; ++rg) {
            pw[(quad * 4 + rg) * 40 + l15] = to_fp8(p0[rg]);
            pw[(quad * 4 + rg) * 40 + 16 + l15] = to_fp8(p1[rg]);
        }
        long pf = *(const long*)&pw[l15 * 40 + quad * 8];
        // PV: paired b128 reads = 2 dn per load
        __builtin_amdgcn_s_setprio(1);
#pragma unroll
        for (int dnp = 0; dnp < 16; ++dnp) {
            longx2 vf = *(const longx2*)&vb2[quad * 4096 + (dnp * 16 + l15) * 16];
            oacc[2 * dnp]     = __builtin_amdgcn_mfma_f32_16x16x32_fp8_fp8(pf, vf[0], oacc[2 * dnp], 0, 0, 0);
            oacc[2 * dnp + 1] = __builtin_amdgcn_mfma_f32_16x16x32_fp8_fp8(pf, vf[1], oacc[2 * dnp + 1], 0, 0, 0);
        }
        __builtin_amdgcn_s_setprio(0);

        // ---- flush segment at tile boundary / end of span ----
        if (last || newtile) {
            int ord = b_ * 128 + f_ * 16 + tif;   // q-tile ordinal 0..255
            if (tid == 0) {
                int s = atomicAdd(counter, 1);
                int pos = atomicAdd(&cnt[ord], 1);
                slist[ord * 8 + pos] = s;
                slot_sh = s;
            }
            __syncthreads();
            int slot = slot_sh;
#pragma unroll
            for (int rg = 0; rg < 4; ++rg)
                for (int d = 1; d < 16; d <<= 1)
                    l_i[rg] += __shfl_xor(l_i[rg], d);
            float rinv[4];
#pragma unroll
            for (int rg = 0; rg < 4; ++rg) rinv[rg] = 1.f / l_i[rg];
            bf16* pp2 = part + ((size_t)slot * 64 + wave * 16) * C_DIM;
#pragma unroll
            for (int dn = 0; dn < 32; ++dn)
#pragma unroll
                for (int rg = 0; rg < 4; ++rg)
                    pp2[(size_t)(quad * 4 + rg) * C_DIM + dn * 16 + l15] =
                        (bf16)(oacc[dn][rg] * rinv[rg]);
            if (l15 == 0) {
#pragma unroll
                for (int rg = 0; rg < 4; ++rg)
                    lsum[slot * 64 + wave * 16 + quad * 4 + rg] = l_i[rg];
            }
            if (!last) {
#pragma unroll
                for (int dn = 0; dn < 32; ++dn) oacc[dn] = (f32x4){0.f, 0.f, 0.f, 0.f};
#pragma unroll
                for (int rg = 0; rg < 4; ++rg) l_i[rg] = 0.f;
                int nqbase = (nf * 16 + ntif) * 64 + wave * 16;
                const unsigned char* qp = q + (size_t)(nb * S_DIM + nqbase + l15) * C_DIM;
#pragma unroll
                for (int ks = 0; ks < 16; ++ks)
                    qf[ks] = *(const long*)&qp[ks * 32 + quad * 8];
            }
        }
        b_ = nb; f_ = nf; L = nL; tif = ntif; cw = ncw;
        __syncthreads();   // drains prefetch + all waves done with buffers
    }
}

// ------------- Kernel 4b: non-split fallback flash attention -------------
__global__ __launch_bounds__(256, 2) void attn_kernel(const unsigned char* __restrict__ q,
                                                      const unsigned char* __restrict__ k,
                                                      const unsigned char* __restrict__ vt,
                                                      bf16* __restrict__ ob) {
    __shared__ unsigned char Ks[2][16384];
    __shared__ unsigned char Vs[2][16384];
    __shared__ unsigned char Ps[4][16 * 40];
    int id = blockIdx.x;
    int b = id >> 7;
    int t = id & 127;
    int q0 = t * 64;
    int kc1 = ((t >> 4) + 1) << 10;
    int tid  = threadIdx.x;
    int lane = tid & 63;
    int wave = tid >> 6;
    int l15  = lane & 15;
    int quad = lane >> 4;
    int qbase = q0 + wave * 16;
    int nchunks = kc1 >> 5;

    long qf[16];
    const unsigned char* qp = q + (size_t)(b * S_DIM + qbase + l15) * C_DIM;
#pragma unroll
    for (int ks = 0; ks < 16; ++ks)
        qf[ks] = *(const long*)&qp[ks * 32 + quad * 8];

    f32x4 oacc[32] = {};
    float l_i[4] = {0.f, 0.f, 0.f, 0.f};
    const float scale = 0.044194173824159216f;

    const unsigned char* kbase = k  + ((size_t)(b * 256) << 14);
    const unsigned char* vbase = vt + ((size_t)(b * 256) << 14);

#pragma unroll
    for (int j = 0; j < 4; ++j) {
        int base = (j * 4 + wave) * 1024;
        async_ld16(kbase + base + lane * 16, &Ks[0][base]);
        async_ld16(vbase + base + lane * 16, &Vs[0][base]);
    }
    __syncthreads();

    for (int p = 0; p < nchunks; ++p) {
        int pn = (p + 1 < nchunks) ? (p + 1) : p;
        const unsigned char* ksub = kbase + ((size_t)pn << 14);
        const unsigned char* vsub = vbase + ((size_t)pn << 14);
        unsigned char* kd = Ks[(p + 1) & 1];
        unsigned char* vd = Vs[(p + 1) & 1];
#pragma unroll
        for (int j = 0; j < 4; ++j) {
            int base = (j * 4 + wave) * 1024;
            async_ld16(ksub + base + lane * 16, kd + base);
            async_ld16(vsub + base + lane * 16, vd + base);
        }
        const unsigned char* kb = Ks[p & 1];
        const unsigned char* vb = Vs[p & 1];
        f32x4 st[2] = {};
#pragma unroll
        for (int nt = 0; nt < 2; ++nt) {
#pragma unroll
            for (int pp = 0; pp < 8; ++pp) {
                longx2 kf = *(const longx2*)&kb[(((pp * 4 + quad) * 32) + nt * 16 + l15) * 16];
                st[nt] = __builtin_amdgcn_mfma_f32_16x16x32_fp8_fp8(qf[2 * pp], kf[0], st[nt], 0, 0, 0);
                st[nt] = __builtin_amdgcn_mfma_f32_16x16x32_fp8_fp8(qf[2 * pp + 1], kf[1], st[nt], 0, 0, 0);
            }
        }
        float p0[4], p1[4];
#pragma unroll
        for (int rg = 0; rg < 4; ++rg) {
            p0[rg] = __expf(st[0][rg] * scale);
            p1[rg] = __expf(st[1][rg] * scale);
            l_i[rg] += p0[rg] + p1[rg];
        }
        unsigned char* pw = Ps[wave];
#pragma unroll
        for (int rg = 0; rg < 4; ++rg) {
            pw[(quad * 4 + rg) * 40 + l15] = to_fp8(p0[rg]);
            pw[(quad * 4 + rg) * 40 + 16 + l15] = to_fp8(p1[rg]);
        }
        long pf = *(const long*)&pw[l15 * 40 + quad * 8];
#pragma unroll
        for (int dnp = 0; dnp < 16; ++dnp) {
            longx2 vf = *(const longx2*)&vb[quad * 4096 + (dnp * 16 + l15) * 16];
            oacc[2 * dnp]     = __builtin_amdgcn_mfma_f32_16x16x32_fp8_fp8(pf, vf[0], oacc[2 * dnp], 0, 0, 0);
            oacc[2 * dnp + 1] = __builtin_amdgcn_mfma_f32_16x16x32_fp8_fp8(pf, vf[1], oacc[2 * dnp + 1], 0, 0, 0);
        }
        __syncthreads();
    }
#pragma unroll
    for (int rg = 0; rg < 4; ++rg)
        for (int d = 1; d < 16; d <<= 1)
            l_i[rg] += __shfl_xor(l_i[rg], d);
    float rinv[4];
#pragma unroll
    for (int rg = 0; rg < 4; ++rg) rinv[rg] = 1.f / l_i[rg];
    bf16* op = ob + (size_t)(b * S_DIM + qbase) * C_DIM;
#pragma unroll
    for (int dn = 0; dn < 32; ++dn)
#pragma unroll
        for (int rg = 0; rg < 4; ++rg)
            op[(size_t)(quad * 4 + rg) * C_DIM + dn * 16 + l15] =
                (bf16)(oacc[dn][rg] * rinv[rg]);
}

// ------------- Kernel 5: split-K combine (slot-list weighted sum) --------
// grid 256 x 4: blockIdx.y selects a 128-channel quarter.
__global__ __launch_bounds__(256) void combine_kernel(const bf16* __restrict__ part,
                                                      const float* __restrict__ lsum,
                                                      bf16* __restrict__ ob,
                                                      const int* __restrict__ cnt,
                                                      const int* __restrict__ slist) {
    int id = blockIdx.x;            // q-tile ordinal 0..255
    int b  = id >> 7;
    int q0 = (id & 127) * 64;
    int U  = cnt[id];               // 1..~5 segments
    int qq = threadIdx.x >> 2;      // 0..63
    int cr = threadIdx.x & 3;       // 32-ch sub-segment
    int cbase = blockIdx.y * 128 + cr * 32;
    int sl[8];
    float w[8];
    float D = 0.f;
    for (int u = 0; u < U; ++u) {
        sl[u] = slist[id * 8 + u];
        w[u] = lsum[sl[u] * 64 + qq];
        D += w[u];
    }
    float Dinv = 1.f / D;
    for (int u = 0; u < U; ++u) w[u] *= Dinv;
    bf16* op = ob + (size_t)(b * S_DIM + q0 + qq) * C_DIM + cbase;
    for (int ch = 0; ch < 4; ++ch) {
        float acc[8] = {};
        for (int u = 0; u < U; ++u) {
            bf16x8 pv = *(const bf16x8*)&part[((size_t)sl[u] * 64 + qq) * C_DIM + cbase + ch * 8];
#pragma unroll
            for (int j = 0; j < 8; ++j) acc[j] += w[u] * (float)pv[j];
        }
        bf16x8 o8;
#pragma unroll
        for (int j = 0; j < 8; ++j) o8[j] = (bf16)acc[j];
        *(bf16x8*)&op[ch * 8] = o8;
    }
}

extern "C" void kernel_launch(void* const* d_in, const int* in_sizes, int n_in,
                              void* d_out, int out_size, void* d_ws, size_t ws_size,
                              hipStream_t stream) {
    const void* x     = d_in[0];
    const void* gamma = d_in[1];
    const void* wq    = d_in[2];
    const void* bq    = d_in[3];
    const void* wk    = d_in[4];
    const void* bk    = d_in[5];
    const void* wv    = d_in[6];
    const void* bv    = d_in[7];
    const void* wo    = d_in[8];
    const void* bo    = d_in[9];

    char* ws = (char*)d_ws;
    int*   flag    = (int*)ws;                 // [0]=flag, [16]=slot counter, [64..320)=cnt
    int*   counter = (int*)(ws + 64);
    int*   cntp    = (int*)(ws + 256);
    int*   slist   = (int*)(ws + 0x12000);     // 256 q-tiles x 8 slots (8 KB)
    bf16* wqb = (bf16*)(ws + 0x20000);   // 4 weights contiguous, 512 KB each
    bf16* wkb = (bf16*)(ws + 0xA0000);
    bf16* wvb = (bf16*)(ws + 0x120000);
    bf16* wob = (bf16*)(ws + 0x1A0000);
    float* lsum_buf = (float*)(ws + 0x240000);                  // <=768 slots x 64 f32
    bf16* hn  = (bf16*)(ws + 0x400000);                         // 16 MB
    unsigned char* qb  = (unsigned char*)(ws + 0x1400000);      // 8 MB (fp8)
    unsigned char* kb  = (unsigned char*)(ws + 0x1C00000);      // 8 MB
    unsigned char* vtb = (unsigned char*)(ws + 0x2400000);      // 8 MB
    bf16* ob  = (bf16*)(ws + 0x2C00000);                        // 16 MB
    bf16* part = (bf16*)(ws + 0x5400000);                       // <=768 slots x 64 x 512 bf16 (50.3 MB)

    const size_t ws_needed_split = 0x5400000ull + 768ull * 64 * 512 * 2;
    int split = (ws_size >= ws_needed_split) ? 1 : 0;

    hipLaunchKernelGGL(detect_kernel, dim3(1), dim3(64), 0, stream,
                       (const unsigned short*)x, flag);
    hipLaunchKernelGGL(convert_kernel, dim3(1024, 4), dim3(256), 0, stream,
                       wq, wk, wv, wo, wqb, flag);
    hipLaunchKernelGGL(rmshn_kernel, dim3(512), dim3(256), 0, stream, x, gamma, hn, flag);
    hipLaunchKernelGGL(gemm_qkv_kernel, dim3(128, 4), dim3(256), 0, stream,
                       hn, wqb, wkb, wvb, wq, wk, wv, bq, bk, bv, qb, kb, vtb, flag);
    if (split) {
        hipLaunchKernelGGL(attn_split_kernel, dim3(512), dim3(256), 0, stream,
                           qb, kb, vtb, part, lsum_buf, counter, cntp, slist);
        hipLaunchKernelGGL(combine_kernel, dim3(256, 4), dim3(256), 0, stream,
                           part, lsum_buf, ob, cntp, slist);
    } else {
        hipLaunchKernelGGL(attn_kernel, dim3(256), dim3(256), 0, stream, qb, kb, vtb, ob);
    }
    hipLaunchKernelGGL(gemm_kernel, dim3(128, 4), dim3(256), 0, stream, ob, wob, wo, bo, x, d_out, flag);
}